// Round 5
// baseline (2046.720 us; speedup 1.0000x reference)
//
#include <hip/hip_runtime.h>

#define NN 50000
#define EE 1600000
#define RR 16
#define NBASE 4
#define FINF 128
#define HD 128
#define NG 64
#define NCLS 2
#define NRSEG (NN*RR)   // 800000

typedef __attribute__((ext_vector_type(8))) short short8;
typedef __attribute__((ext_vector_type(4))) float f32x4;
typedef unsigned short u16;
typedef unsigned int u32;

__device__ __forceinline__ float bflo(u32 u){ return __builtin_bit_cast(float, u << 16); }
__device__ __forceinline__ float bfhi(u32 u){ return __builtin_bit_cast(float, u & 0xFFFF0000u); }
__device__ __forceinline__ u16 f2bf(float f){
  u32 u = __builtin_bit_cast(u32, f);
  u += 0x7FFFu + ((u >> 16) & 1u);
  return (u16)(u >> 16);
}
__device__ __forceinline__ u32 pack2(float a, float b){
  return (u32)f2bf(a) | ((u32)f2bf(b) << 16);
}
__device__ __forceinline__ float ldf(const void* p, int i, int isbf){
  return isbf ? bflo((u32)((const u16*)p)[i]) : ((const float*)p)[i];
}

// ---------------- dtype detector ----------------
__global__ void k_detect(const u32* __restrict__ xw, int* __restrict__ flag){
  __shared__ int votes;
  if (threadIdx.x == 0) votes = 0;
  __syncthreads();
  u32 w = xw[threadIdx.x];
  int e = (w >> 7) & 0xFF;
  if (e >= 100 && e <= 129) atomicAdd(&votes, 1);
  __syncthreads();
  if (threadIdx.x == 0) flag[0] = (votes >= 192) ? 1 : 0;
}

// ---------------- CSR build ----------------

__global__ void k_hist(const int* __restrict__ dst, const int* __restrict__ et,
                       int* __restrict__ cnt){
  int e = blockIdx.x*256 + threadIdx.x;
  if (e < EE) atomicAdd(&cnt[dst[e]*RR + et[e]], 1);
}

__global__ void k_scan1(const int* __restrict__ cnt, int* __restrict__ off,
                        int* __restrict__ bsum){
  __shared__ int sh[256];
  int tid = threadIdx.x;
  int i = blockIdx.x*256 + tid;
  int v = (i < NRSEG) ? cnt[i] : 0;
  sh[tid] = v; __syncthreads();
  for (int d=1; d<256; d<<=1){
    int t = (tid >= d) ? sh[tid-d] : 0;
    __syncthreads();
    sh[tid] += t;
    __syncthreads();
  }
  if (i < NRSEG) off[i] = sh[tid] - v;
  if (tid == 255) bsum[blockIdx.x] = sh[255];
}

__global__ __launch_bounds__(1024) void k_scan2(int* __restrict__ bsum, int nb){
  __shared__ int sh[1024];
  __shared__ int carry;
  int tid = threadIdx.x;
  if (tid == 0) carry = 0;
  __syncthreads();
  for (int base=0; base<nb; base+=1024){
    int i = base + tid;
    int v = (i < nb) ? bsum[i] : 0;
    int orig = v;
    sh[tid] = v; __syncthreads();
    for (int d=1; d<1024; d<<=1){
      int t = (tid >= d) ? sh[tid-d] : 0;
      __syncthreads();
      sh[tid] += t;
      __syncthreads();
    }
    int total = sh[1023];
    int excl = sh[tid] - orig + carry;
    if (i < nb) bsum[i] = excl;
    __syncthreads();
    if (tid == 0) carry += total;
    __syncthreads();
  }
}

__global__ void k_scan3(const int* __restrict__ cnt, int* __restrict__ off,
                        const int* __restrict__ bsum){
  int i = blockIdx.x*256 + threadIdx.x;
  if (i < NRSEG){
    int o = off[i] + bsum[blockIdx.x];
    off[i] = o;
    if (i == NRSEG-1) off[NRSEG] = o + cnt[i];
  }
}

__global__ void k_scatter(const int* __restrict__ src, const int* __restrict__ dst,
                          const int* __restrict__ et, const int* __restrict__ off,
                          int* __restrict__ cnt, int* __restrict__ esrc){
  int e = blockIdx.x*256 + threadIdx.x;
  if (e < EE){
    int seg = dst[e]*RR + et[e];
    int p = atomicSub(&cnt[seg], 1) - 1;
    esrc[off[seg] + p] = src[e];
  }
}

// ---------------- weights: WT[r][o][i] = sum_b comp[r,b]*bases[b][i][o]; WT[16]=root^T ----

__global__ void k_weights(const void* __restrict__ bases, const void* __restrict__ comp,
                          const void* __restrict__ root, u16* __restrict__ WT,
                          const int* __restrict__ flagp){
  int idx = blockIdx.x*256 + threadIdx.x;
  if (idx >= 17*16384) return;
  int isbf = flagp[0];
  int r = idx >> 14;
  int o = (idx >> 7) & 127;
  int i = idx & 127;
  float v;
  if (r < RR){
    v = 0.f;
    #pragma unroll
    for (int b=0;b<NBASE;b++)
      v += ldf(comp, r*NBASE+b, isbf) * ldf(bases, (b*FINF + i)*HD + o, isbf);
  } else {
    v = ldf(root, i*HD + o, isbf);
  }
  WT[idx] = f2bf(v);
}

// ---------------- fused aggregate + GEMM layer (v3) ----------------
// 64 nodes/block, 256 threads (4 waves). Wave w owns nodes [n0+16w, n0+16w+16).
// Per relation rr: wave-per-segment gather — lane = feature pair, edge row loads
// fully coalesced (256 B bf16 / 512 B fp32 per row), edge-list offsets broadcast
// to SGPRs via readlane so esrc reads become scalar (constant-cache) loads, and
// the 16 segments are interleaved in a t-loop so 16 row loads are in flight.
// B tile staged in LDS (R3-proven). LDS 52.2 KB -> 3 blocks/CU.

#define TN 64

__global__ __launch_bounds__(256) void k_layer(
    const void* __restrict__ xin, const u16* __restrict__ WT,
    const void* __restrict__ bias, const int* __restrict__ off,
    const int* __restrict__ esrc, u16* __restrict__ hout,
    const int* __restrict__ flagp, int xin_is_input, int relu)
{
  __shared__ __align__(16) u16 Abuf[TN*136];
  __shared__ __align__(16) u16 Bbuf[128*136];
  int tid = threadIdx.x;
  int n0 = blockIdx.x * TN;
  int isbf_in = flagp[0];
  int isbf_x  = xin_is_input ? isbf_in : 1;

  int wv = tid >> 6;
  int lane = tid & 63;
  int mrow = lane & 15;
  int quad = lane >> 4;
  int nwbase = n0 + wv*16;          // wave's first node

  f32x4 acc[8];
  #pragma unroll
  for (int c=0;c<8;c++){ f32x4 z = {0.f,0.f,0.f,0.f}; acc[c] = z; }

  for (int rr=0; rr<17; ++rr){
    __syncthreads();   // LDS free from previous iteration's MFMA reads
    // ---- stage B = WT[rr], padded stride 136 (256 thr x 128 B = 32 KB) ----
    {
      int brow = tid >> 1;
      int bh = tid & 1;
      const uint4* s = (const uint4*)(WT + rr*16384 + brow*128 + bh*64);
      uint4* d = (uint4*)(Bbuf + brow*136 + bh*64);
      #pragma unroll
      for (int q=0;q<8;q++) d[q] = s[q];
    }
    // ---- build A rows for this wave's 16 nodes ----
    if (rr < RR){
      // lanes 0..15 load e0 of segment i, lanes 16..31 load e1 (=off[seg+1])
      int evv = 0;
      if (lane < 32){
        int i = lane & 15;
        int add1 = (lane >> 4) & 1;
        int node = nwbase + i;
        int segi = (node < NN) ? (node*RR + rr + add1) : NRSEG;
        evv = off[segi];
      }
      int s_e0[16], s_cnt[16];
      int maxc = 0;
      #pragma unroll
      for (int i=0;i<16;i++){
        int e0 = __builtin_amdgcn_readlane(evv, i);
        int e1 = __builtin_amdgcn_readlane(evv, i+16);
        s_e0[i] = e0;
        int c = e1 - e0;
        s_cnt[i] = c;
        maxc = (c > maxc) ? c : maxc;
      }
      float fa0[16], fa1[16];
      #pragma unroll
      for (int i=0;i<16;i++){ fa0[i]=0.f; fa1[i]=0.f; }
      if (isbf_x){
        for (int t=0; t<maxc; ++t){
          int srcs[16];
          #pragma unroll
          for (int i=0;i<16;i++)
            srcs[i] = (t < s_cnt[i]) ? esrc[s_e0[i] + t] : -1;   // uniform -> s_load
          #pragma unroll
          for (int i=0;i<16;i++){
            if (srcs[i] >= 0){
              u32 w = *(const u32*)((const u16*)xin + (size_t)srcs[i]*HD + lane*2);
              fa0[i] += bflo(w); fa1[i] += bfhi(w);
            }
          }
        }
      } else {
        for (int t=0; t<maxc; ++t){
          int srcs[16];
          #pragma unroll
          for (int i=0;i<16;i++)
            srcs[i] = (t < s_cnt[i]) ? esrc[s_e0[i] + t] : -1;
          #pragma unroll
          for (int i=0;i<16;i++){
            if (srcs[i] >= 0){
              float2 v = *(const float2*)((const float*)xin + (size_t)srcs[i]*HD + lane*2);
              fa0[i] += v.x; fa1[i] += v.y;
            }
          }
        }
      }
      #pragma unroll
      for (int i=0;i<16;i++){
        float inv = 1.0f / (float)(s_cnt[i] > 0 ? s_cnt[i] : 1);
        *(u32*)(Abuf + (wv*16 + i)*136 + lane*2) = pack2(fa0[i]*inv, fa1[i]*inv);
      }
    } else {
      // root pass: A row = x[node]
      #pragma unroll
      for (int i=0;i<16;i++){
        int node = nwbase + i;
        u32 pv = 0;
        if (node < NN){
          if (isbf_x){
            pv = *(const u32*)((const u16*)xin + (size_t)node*HD + lane*2);
          } else {
            float2 v = *(const float2*)((const float*)xin + (size_t)node*HD + lane*2);
            pv = pack2(v.x, v.y);
          }
        }
        *(u32*)(Abuf + (wv*16 + i)*136 + lane*2) = pv;
      }
    }
    __syncthreads();
    // ---- MFMA: C[64x128] += A[64x128] @ W[rr][128x128] ----
    short8 af[4];
    #pragma unroll
    for (int ks=0;ks<4;ks++)
      af[ks] = *(const short8*)(Abuf + (wv*16 + mrow)*136 + ks*32 + quad*8);
    #pragma unroll
    for (int c=0;c<8;c++){
      #pragma unroll
      for (int ks=0;ks<4;ks++){
        short8 bf = *(const short8*)(Bbuf + (c*16 + mrow)*136 + ks*32 + quad*8);
        acc[c] = __builtin_amdgcn_mfma_f32_16x16x32_bf16(af[ks], bf, acc[c], 0, 0, 0);
      }
    }
  }
  // epilogue: bias (+relu), NaN firewall, store bf16
  #pragma unroll
  for (int c=0;c<8;c++){
    int col = c*16 + mrow;
    float bv = ldf(bias, col, isbf_in);
    #pragma unroll
    for (int rg=0;rg<4;rg++){
      int row = wv*16 + quad*4 + rg;
      int n = n0 + row;
      if (n < NN){
        float v = acc[c][rg] + bv;
        if (relu) v = fmaxf(v, 0.f);
        if (!(v == v)) v = 0.f;
        hout[(size_t)n*HD + col] = f2bf(v);
      }
    }
  }
}

// ---------------- global mean pool + concat + linear head ----------------

__global__ __launch_bounds__(256) void k_pool_head(
    const u16* __restrict__ h, const int* __restrict__ batch,
    const int* __restrict__ rlab, const void* __restrict__ rel_emb,
    const void* __restrict__ lin_w, const void* __restrict__ lin_b,
    void* __restrict__ out, const int* __restrict__ flagp)
{
  int g = blockIdx.x;
  int isbf = flagp[0];
  __shared__ int bounds[2];
  __shared__ float psum[2][128];
  __shared__ float red[4];
  if (threadIdx.x == 0){
    int lo=0, hi=NN;
    while (lo < hi){ int m=(lo+hi)>>1; if (batch[m] < g) lo=m+1; else hi=m; }
    bounds[0] = lo;
    int lo2=lo, hi2=NN;
    while (lo2 < hi2){ int m=(lo2+hi2)>>1; if (batch[m] < g+1) lo2=m+1; else hi2=m; }
    bounds[1] = lo2;
  }
  __syncthreads();
  int lo = bounds[0], hi = bounds[1];
  int f = threadIdx.x & 127;
  int s = threadIdx.x >> 7;
  float acc = 0.f;
  for (int n = lo + s; n < hi; n += 2) acc += bflo((u32)h[(size_t)n*HD + f]);
  psum[s][f] = acc;
  __syncthreads();
  if (threadIdx.x < 128){
    int cn = hi - lo;
    float pooled = (psum[0][f] + psum[1][f]) / (float)(cn > 0 ? cn : 1);
    int rl = rlab[g];
    float re = ldf(rel_emb, rl*HD + f, isbf);
    float v0 = pooled * ldf(lin_w, f*NCLS+0, isbf) + re * ldf(lin_w, (HD+f)*NCLS+0, isbf);
    float v1 = pooled * ldf(lin_w, f*NCLS+1, isbf) + re * ldf(lin_w, (HD+f)*NCLS+1, isbf);
    #pragma unroll
    for (int o=32;o>0;o>>=1){ v0 += __shfl_down(v0,o); v1 += __shfl_down(v1,o); }
    int ln = threadIdx.x & 63, wvv = threadIdx.x >> 6;
    if (ln == 0){ red[wvv*2] = v0; red[wvv*2+1] = v1; }
  }
  __syncthreads();
  if (threadIdx.x == 0){
    float o0 = red[0] + red[2] + ldf(lin_b, 0, isbf);
    float o1 = red[1] + red[3] + ldf(lin_b, 1, isbf);
    if (isbf){
      ((u16*)out)[g*NCLS+0] = f2bf(o0);
      ((u16*)out)[g*NCLS+1] = f2bf(o1);
    } else {
      ((float*)out)[g*NCLS+0] = o0;
      ((float*)out)[g*NCLS+1] = o1;
    }
  }
}

// ---------------- launch ----------------

extern "C" void kernel_launch(void* const* d_in, const int* in_sizes, int n_in,
                              void* d_out, int out_size, void* d_ws, size_t ws_size,
                              hipStream_t stream)
{
  (void)in_sizes; (void)n_in; (void)out_size; (void)ws_size;
  const void* x      = d_in[0];
  const int* eidx    = (const int*)d_in[1];
  const int* etype   = (const int*)d_in[2];
  const int* batch   = (const int*)d_in[3];
  const int* rlab    = (const int*)d_in[4];
  const void* rel_emb = d_in[6];
  const void* basesA[3] = {d_in[7],  d_in[11], d_in[15]};
  const void* compA[3]  = {d_in[8],  d_in[12], d_in[16]};
  const void* rootA[3]  = {d_in[9],  d_in[13], d_in[17]};
  const void* biasA[3]  = {d_in[10], d_in[14], d_in[18]};
  const void* lin_w  = d_in[19];
  const void* lin_b  = d_in[20];

  char* p = (char*)d_ws;
  auto alloc = [&](size_t bytes)->char*{ char* r = p; p += (bytes + 255) & ~(size_t)255; return r; };
  int*   flag   = (int*)  alloc(256);
  int*   cnt    = (int*)  alloc((size_t)NRSEG*4);
  int*   off    = (int*)  alloc((size_t)(NRSEG+1)*4);
  int*   esrc   = (int*)  alloc((size_t)(EE+64)*4);
  int*   bsum   = (int*)  alloc(4096*4);
  u16*   WT     = (u16*)  alloc((size_t)17*16384*2);
  u16*   h1     = (u16*)  alloc((size_t)NN*HD*2);
  u16*   h2     = (u16*)  alloc((size_t)NN*HD*2);

  const int* src_in = eidx;        // edge_index[0]
  const int* dst_in = eidx + EE;   // edge_index[1]

  k_detect <<<1, 256, 0, stream>>>((const u32*)x, flag);
  hipMemsetAsync(cnt, 0, (size_t)NRSEG*4, stream);
  k_hist   <<<EE/256,    256, 0, stream>>>(dst_in, etype, cnt);
  k_scan1  <<<NRSEG/256, 256, 0, stream>>>(cnt, off, bsum);
  k_scan2  <<<1,        1024, 0, stream>>>(bsum, NRSEG/256);
  k_scan3  <<<NRSEG/256, 256, 0, stream>>>(cnt, off, bsum);
  k_scatter<<<EE/256,    256, 0, stream>>>(src_in, dst_in, etype, off, cnt, esrc);

  const void* xin = x;
  u16* houts[3] = {h1, h2, h1};
  for (int l=0;l<3;l++){
    k_weights<<<1088, 256, 0, stream>>>(basesA[l], compA[l], rootA[l], WT, flag);
    k_layer<<<(NN + TN - 1)/TN, 256, 0, stream>>>(xin, WT, biasA[l], off, esrc,
                                                  houts[l], flag, (l == 0) ? 1 : 0,
                                                  (l < 2) ? 1 : 0);
    xin = houts[l];
  }
  k_pool_head<<<NG, 256, 0, stream>>>(houts[2], batch, rlab, rel_emb, lin_w, lin_b,
                                      d_out, flag);
}

// Round 6
// 1266.807 us; speedup vs baseline: 1.6157x; 1.6157x over previous
//
#include <hip/hip_runtime.h>

#define NN 50000
#define EE 1600000
#define RR 16
#define NBASE 4
#define FINF 128
#define HD 128
#define NG 64
#define NCLS 2
#define NRSEG (NN*RR)   // 800000

typedef __attribute__((ext_vector_type(8))) short short8;
typedef __attribute__((ext_vector_type(4))) float f32x4;
typedef unsigned short u16;
typedef unsigned int u32;

__device__ __forceinline__ float bflo(u32 u){ return __builtin_bit_cast(float, u << 16); }
__device__ __forceinline__ float bfhi(u32 u){ return __builtin_bit_cast(float, u & 0xFFFF0000u); }
__device__ __forceinline__ u16 f2bf(float f){
  u32 u = __builtin_bit_cast(u32, f);
  u += 0x7FFFu + ((u >> 16) & 1u);
  return (u16)(u >> 16);
}
__device__ __forceinline__ u32 pack2(float a, float b){
  return (u32)f2bf(a) | ((u32)f2bf(b) << 16);
}
__device__ __forceinline__ float ldf(const void* p, int i, int isbf){
  return isbf ? bflo((u32)((const u16*)p)[i]) : ((const float*)p)[i];
}

// ---------------- dtype detector ----------------
__global__ void k_detect(const u32* __restrict__ xw, int* __restrict__ flag){
  __shared__ int votes;
  if (threadIdx.x == 0) votes = 0;
  __syncthreads();
  u32 w = xw[threadIdx.x];
  int e = (w >> 7) & 0xFF;
  if (e >= 100 && e <= 129) atomicAdd(&votes, 1);
  __syncthreads();
  if (threadIdx.x == 0) flag[0] = (votes >= 192) ? 1 : 0;
}

// ---------------- CSR build (REL-MAJOR: seg = rel*NN + dst) ----------------

__global__ void k_hist(const int* __restrict__ src_unused, const int* __restrict__ dst,
                       const int* __restrict__ et, int* __restrict__ cnt){
  int e = blockIdx.x*256 + threadIdx.x;
  if (e < EE) atomicAdd(&cnt[et[e]*NN + dst[e]], 1);
}

__global__ void k_scan1(const int* __restrict__ cnt, int* __restrict__ off,
                        int* __restrict__ bsum){
  __shared__ int sh[256];
  int tid = threadIdx.x;
  int i = blockIdx.x*256 + tid;
  int v = (i < NRSEG) ? cnt[i] : 0;
  sh[tid] = v; __syncthreads();
  for (int d=1; d<256; d<<=1){
    int t = (tid >= d) ? sh[tid-d] : 0;
    __syncthreads();
    sh[tid] += t;
    __syncthreads();
  }
  if (i < NRSEG) off[i] = sh[tid] - v;
  if (tid == 255) bsum[blockIdx.x] = sh[255];
}

__global__ __launch_bounds__(1024) void k_scan2(int* __restrict__ bsum, int nb){
  __shared__ int sh[1024];
  __shared__ int carry;
  int tid = threadIdx.x;
  if (tid == 0) carry = 0;
  __syncthreads();
  for (int base=0; base<nb; base+=1024){
    int i = base + tid;
    int v = (i < nb) ? bsum[i] : 0;
    int orig = v;
    sh[tid] = v; __syncthreads();
    for (int d=1; d<1024; d<<=1){
      int t = (tid >= d) ? sh[tid-d] : 0;
      __syncthreads();
      sh[tid] += t;
      __syncthreads();
    }
    int total = sh[1023];
    int excl = sh[tid] - orig + carry;
    if (i < nb) bsum[i] = excl;
    __syncthreads();
    if (tid == 0) carry += total;
    __syncthreads();
  }
}

__global__ void k_scan3(const int* __restrict__ cnt, int* __restrict__ off,
                        const int* __restrict__ bsum){
  int i = blockIdx.x*256 + threadIdx.x;
  if (i < NRSEG){
    int o = off[i] + bsum[blockIdx.x];
    off[i] = o;
    if (i == NRSEG-1) off[NRSEG] = o + cnt[i];
  }
}

__global__ void k_scatter(const int* __restrict__ src, const int* __restrict__ dst,
                          const int* __restrict__ et, const int* __restrict__ off,
                          int* __restrict__ cnt, int* __restrict__ esrc){
  int e = blockIdx.x*256 + threadIdx.x;
  if (e < EE){
    int seg = et[e]*NN + dst[e];
    int p = atomicSub(&cnt[seg], 1) - 1;
    esrc[off[seg] + p] = src[e];
  }
}

// ---------------- weights: WT[r][o][i] = sum_b comp[r,b]*bases[b][i][o]; WT[16]=root^T ----

__global__ void k_weights(const void* __restrict__ bases, const void* __restrict__ comp,
                          const void* __restrict__ root, u16* __restrict__ WT,
                          const int* __restrict__ flagp){
  int idx = blockIdx.x*256 + threadIdx.x;
  if (idx >= 17*16384) return;
  int isbf = flagp[0];
  int r = idx >> 14;
  int o = (idx >> 7) & 127;
  int i = idx & 127;
  float v;
  if (r < RR){
    v = 0.f;
    #pragma unroll
    for (int b=0;b<NBASE;b++)
      v += ldf(comp, r*NBASE+b, isbf) * ldf(bases, (b*FINF + i)*HD + o, isbf);
  } else {
    v = ldf(root, i*HD + o, isbf);
  }
  WT[idx] = f2bf(v);
}

// ---------------- fused aggregate + GEMM layer (v4) ----------------
// 64 nodes/block, 256 threads (4 waves). Rel-major CSR: per rr, a wave's 16
// nodes own ONE contiguous esrc span (~32 edges), node-sorted. Wave walks the
// span with wave-uniform e: esrc[e] = scalar load; row load = u32/lane = 256 B
// fully coalesced; per-lane 2 fp32 running sums; flush packed bf16 mean into
// Abuf at uniform node boundaries (readlane on reg-held offset window).
// Chunk-unroll x8 -> 8 independent row loads in flight per wave.

#define TN 64

__global__ __launch_bounds__(256) void k_layer(
    const void* __restrict__ xin, const u16* __restrict__ WT,
    const void* __restrict__ bias, const int* __restrict__ off,
    const int* __restrict__ esrc, u16* __restrict__ hout,
    const int* __restrict__ flagp, int xin_is_input, int relu)
{
  __shared__ __align__(16) u16 Abuf[TN*136];
  __shared__ __align__(16) u16 Bbuf[128*136];
  int tid = threadIdx.x;
  int n0 = blockIdx.x * TN;
  int isbf_in = flagp[0];
  int isbf_x  = xin_is_input ? isbf_in : 1;

  int wv = tid >> 6;
  int lane = tid & 63;
  int mrow = lane & 15;
  int quad = lane >> 4;
  int nwbase = n0 + wv*16;          // wave's first node

  f32x4 acc[8];
  #pragma unroll
  for (int c=0;c<8;c++){ f32x4 z = {0.f,0.f,0.f,0.f}; acc[c] = z; }

  for (int rr=0; rr<17; ++rr){
    __syncthreads();   // LDS free from previous iteration's MFMA reads
    // ---- stage B = WT[rr], padded stride 136 (256 thr x 128 B = 32 KB) ----
    {
      int brow = tid >> 1;
      int bh = tid & 1;
      const uint4* s = (const uint4*)(WT + rr*16384 + brow*128 + bh*64);
      uint4* d = (uint4*)(Bbuf + brow*136 + bh*64);
      #pragma unroll
      for (int q=0;q<8;q++) d[q] = s[q];
    }
    // ---- build A rows for this wave's 16 nodes ----
    if (rr < RR){
      // lane l<=16 holds off[rr*NN + nwbase + l] (clamped)
      int offv = 0;
      if (lane <= 16){
        int node = nwbase + lane;
        if (node > NN) node = NN;
        offv = off[rr*NN + node];
      }
      int wstart = __builtin_amdgcn_readlane(offv, 0);
      int wend   = __builtin_amdgcn_readlane(offv, 16);
      float a0 = 0.f, a1 = 0.f;
      int idx = 0;
      int cb  = wstart;
      int nb  = __builtin_amdgcn_readlane(offv, 1);
      u16* abase = Abuf + (wv*16)*136 + lane*2;

      auto flushTo = [&](int elim){
        while (idx < 16 && nb <= elim){
          int cnt = nb - cb;
          float inv = (cnt > 0) ? (1.0f/(float)cnt) : 0.0f;
          *(u32*)(abase + idx*136) = pack2(a0*inv, a1*inv);
          a0 = 0.f; a1 = 0.f;
          cb = nb; idx++;
          if (idx < 16) nb = __builtin_amdgcn_readlane(offv, idx+1);
        }
      };

      int e = wstart;
      if (isbf_x){
        const u16* xb = (const u16*)xin;
        for (; e + 8 <= wend; e += 8){
          int s[8];
          #pragma unroll
          for (int j=0;j<8;j++) s[j] = esrc[e+j];
          u32 w[8];
          #pragma unroll
          for (int j=0;j<8;j++) w[j] = *(const u32*)(xb + (size_t)s[j]*HD + lane*2);
          #pragma unroll
          for (int j=0;j<8;j++){
            flushTo(e+j);
            a0 += bflo(w[j]); a1 += bfhi(w[j]);
          }
        }
        for (; e < wend; ++e){
          int s0 = esrc[e];
          u32 w = *(const u32*)(xb + (size_t)s0*HD + lane*2);
          flushTo(e);
          a0 += bflo(w); a1 += bfhi(w);
        }
      } else {
        const float* xb = (const float*)xin;
        for (; e + 8 <= wend; e += 8){
          int s[8];
          #pragma unroll
          for (int j=0;j<8;j++) s[j] = esrc[e+j];
          float2 w[8];
          #pragma unroll
          for (int j=0;j<8;j++) w[j] = *(const float2*)(xb + (size_t)s[j]*HD + lane*2);
          #pragma unroll
          for (int j=0;j<8;j++){
            flushTo(e+j);
            a0 += w[j].x; a1 += w[j].y;
          }
        }
        for (; e < wend; ++e){
          int s0 = esrc[e];
          float2 w = *(const float2*)(xb + (size_t)s0*HD + lane*2);
          flushTo(e);
          a0 += w.x; a1 += w.y;
        }
      }
      flushTo(0x7fffffff);    // flush all remaining (incl. empty) segments
    } else {
      // root pass: A row = x[node], coalesced u32/lane
      #pragma unroll 4
      for (int i=0;i<16;i++){
        int node = nwbase + i;
        u32 pv = 0;
        if (node < NN){
          if (isbf_x){
            pv = *(const u32*)((const u16*)xin + (size_t)node*HD + lane*2);
          } else {
            float2 v = *(const float2*)((const float*)xin + (size_t)node*HD + lane*2);
            pv = pack2(v.x, v.y);
          }
        }
        *(u32*)(Abuf + (wv*16 + i)*136 + lane*2) = pv;
      }
    }
    __syncthreads();
    // ---- MFMA: C[64x128] += A[64x128] @ W[rr][128x128] ----
    short8 af[4];
    #pragma unroll
    for (int ks=0;ks<4;ks++)
      af[ks] = *(const short8*)(Abuf + (wv*16 + mrow)*136 + ks*32 + quad*8);
    #pragma unroll
    for (int c=0;c<8;c++){
      #pragma unroll
      for (int ks=0;ks<4;ks++){
        short8 bf = *(const short8*)(Bbuf + (c*16 + mrow)*136 + ks*32 + quad*8);
        acc[c] = __builtin_amdgcn_mfma_f32_16x16x32_bf16(af[ks], bf, acc[c], 0, 0, 0);
      }
    }
  }
  // epilogue: bias (+relu), NaN firewall, store bf16
  #pragma unroll
  for (int c=0;c<8;c++){
    int col = c*16 + mrow;
    float bv = ldf(bias, col, isbf_in);
    #pragma unroll
    for (int rg=0;rg<4;rg++){
      int row = wv*16 + quad*4 + rg;
      int n = n0 + row;
      if (n < NN){
        float v = acc[c][rg] + bv;
        if (relu) v = fmaxf(v, 0.f);
        if (!(v == v)) v = 0.f;
        hout[(size_t)n*HD + col] = f2bf(v);
      }
    }
  }
}

// ---------------- global mean pool + concat + linear head ----------------

__global__ __launch_bounds__(256) void k_pool_head(
    const u16* __restrict__ h, const int* __restrict__ batch,
    const int* __restrict__ rlab, const void* __restrict__ rel_emb,
    const void* __restrict__ lin_w, const void* __restrict__ lin_b,
    void* __restrict__ out, const int* __restrict__ flagp)
{
  int g = blockIdx.x;
  int isbf = flagp[0];
  __shared__ int bounds[2];
  __shared__ float psum[2][128];
  __shared__ float red[4];
  if (threadIdx.x == 0){
    int lo=0, hi=NN;
    while (lo < hi){ int m=(lo+hi)>>1; if (batch[m] < g) lo=m+1; else hi=m; }
    bounds[0] = lo;
    int lo2=lo, hi2=NN;
    while (lo2 < hi2){ int m=(lo2+hi2)>>1; if (batch[m] < g+1) lo2=m+1; else hi2=m; }
    bounds[1] = lo2;
  }
  __syncthreads();
  int lo = bounds[0], hi = bounds[1];
  int f = threadIdx.x & 127;
  int s = threadIdx.x >> 7;
  float acc = 0.f;
  for (int n = lo + s; n < hi; n += 2) acc += bflo((u32)h[(size_t)n*HD + f]);
  psum[s][f] = acc;
  __syncthreads();
  if (threadIdx.x < 128){
    int cn = hi - lo;
    float pooled = (psum[0][f] + psum[1][f]) / (float)(cn > 0 ? cn : 1);
    int rl = rlab[g];
    float re = ldf(rel_emb, rl*HD + f, isbf);
    float v0 = pooled * ldf(lin_w, f*NCLS+0, isbf) + re * ldf(lin_w, (HD+f)*NCLS+0, isbf);
    float v1 = pooled * ldf(lin_w, f*NCLS+1, isbf) + re * ldf(lin_w, (HD+f)*NCLS+1, isbf);
    #pragma unroll
    for (int o=32;o>0;o>>=1){ v0 += __shfl_down(v0,o); v1 += __shfl_down(v1,o); }
    int ln = threadIdx.x & 63, wvv = threadIdx.x >> 6;
    if (ln == 0){ red[wvv*2] = v0; red[wvv*2+1] = v1; }
  }
  __syncthreads();
  if (threadIdx.x == 0){
    float o0 = red[0] + red[2] + ldf(lin_b, 0, isbf);
    float o1 = red[1] + red[3] + ldf(lin_b, 1, isbf);
    if (isbf){
      ((u16*)out)[g*NCLS+0] = f2bf(o0);
      ((u16*)out)[g*NCLS+1] = f2bf(o1);
    } else {
      ((float*)out)[g*NCLS+0] = o0;
      ((float*)out)[g*NCLS+1] = o1;
    }
  }
}

// ---------------- launch ----------------

extern "C" void kernel_launch(void* const* d_in, const int* in_sizes, int n_in,
                              void* d_out, int out_size, void* d_ws, size_t ws_size,
                              hipStream_t stream)
{
  (void)in_sizes; (void)n_in; (void)out_size; (void)ws_size;
  const void* x      = d_in[0];
  const int* eidx    = (const int*)d_in[1];
  const int* etype   = (const int*)d_in[2];
  const int* batch   = (const int*)d_in[3];
  const int* rlab    = (const int*)d_in[4];
  const void* rel_emb = d_in[6];
  const void* basesA[3] = {d_in[7],  d_in[11], d_in[15]};
  const void* compA[3]  = {d_in[8],  d_in[12], d_in[16]};
  const void* rootA[3]  = {d_in[9],  d_in[13], d_in[17]};
  const void* biasA[3]  = {d_in[10], d_in[14], d_in[18]};
  const void* lin_w  = d_in[19];
  const void* lin_b  = d_in[20];

  char* p = (char*)d_ws;
  auto alloc = [&](size_t bytes)->char*{ char* r = p; p += (bytes + 255) & ~(size_t)255; return r; };
  int*   flag   = (int*)  alloc(256);
  int*   cnt    = (int*)  alloc((size_t)NRSEG*4);
  int*   off    = (int*)  alloc((size_t)(NRSEG+1)*4);
  int*   esrc   = (int*)  alloc((size_t)(EE+64)*4);
  int*   bsum   = (int*)  alloc(4096*4);
  u16*   WT     = (u16*)  alloc((size_t)17*16384*2);
  u16*   h1     = (u16*)  alloc((size_t)NN*HD*2);
  u16*   h2     = (u16*)  alloc((size_t)NN*HD*2);

  const int* src_in = eidx;        // edge_index[0]
  const int* dst_in = eidx + EE;   // edge_index[1]

  k_detect <<<1, 256, 0, stream>>>((const u32*)x, flag);
  hipMemsetAsync(cnt, 0, (size_t)NRSEG*4, stream);
  k_hist   <<<EE/256,    256, 0, stream>>>(src_in, dst_in, etype, cnt);
  k_scan1  <<<NRSEG/256, 256, 0, stream>>>(cnt, off, bsum);
  k_scan2  <<<1,        1024, 0, stream>>>(bsum, NRSEG/256);
  k_scan3  <<<NRSEG/256, 256, 0, stream>>>(cnt, off, bsum);
  k_scatter<<<EE/256,    256, 0, stream>>>(src_in, dst_in, etype, off, cnt, esrc);

  const void* xin = x;
  u16* houts[3] = {h1, h2, h1};
  for (int l=0;l<3;l++){
    k_weights<<<1088, 256, 0, stream>>>(basesA[l], compA[l], rootA[l], WT, flag);
    k_layer<<<(NN + TN - 1)/TN, 256, 0, stream>>>(xin, WT, biasA[l], off, esrc,
                                                  houts[l], flag, (l == 0) ? 1 : 0,
                                                  (l < 2) ? 1 : 0);
    xin = houts[l];
  }
  k_pool_head<<<NG, 256, 0, stream>>>(houts[2], batch, rlab, rel_emb, lin_w, lin_b,
                                      d_out, flag);
}

// Round 8
// 1247.300 us; speedup vs baseline: 1.6409x; 1.0156x over previous
//
#include <hip/hip_runtime.h>

#define NN 50000
#define EE 1600000
#define RR 16
#define NBASE 4
#define FINF 128
#define HD 128
#define NG 64
#define NCLS 2
#define NRSEG (NN*RR)   // 800000

typedef __attribute__((ext_vector_type(8))) short short8;
typedef __attribute__((ext_vector_type(4))) float f32x4;
typedef __attribute__((ext_vector_type(2))) float f32x2;
typedef unsigned short u16;
typedef unsigned int u32;
typedef unsigned char u8;

__device__ __forceinline__ float bflo(u32 u){ return __builtin_bit_cast(float, u << 16); }
__device__ __forceinline__ float bfhi(u32 u){ return __builtin_bit_cast(float, u & 0xFFFF0000u); }
__device__ __forceinline__ u16 f2bf(float f){
  u32 u = __builtin_bit_cast(u32, f);
  u += 0x7FFFu + ((u >> 16) & 1u);
  return (u16)(u >> 16);
}
__device__ __forceinline__ u32 pack2(float a, float b){
  return (u32)f2bf(a) | ((u32)f2bf(b) << 16);
}
__device__ __forceinline__ float ldf(const void* p, int i, int isbf){
  return isbf ? bflo((u32)((const u16*)p)[i]) : ((const float*)p)[i];
}

// ---------------- fp8 e4m3fn helpers ----------------
__device__ __forceinline__ float fp8_manual(u32 b){
  u32 s = (b>>7)&1, e = (b>>3)&15, m = b&7;
  float v;
  if (e==0) v = (float)m * 0.001953125f;                 // m * 2^-9
  else      v = __builtin_bit_cast(float, ((e+120u)<<23) | (m<<20));
  return s ? -v : v;
}
__device__ __forceinline__ u32 f32_to_fp8_manual(float f){
  float cf = fminf(fmaxf(f, -448.f), 448.f);
  u32 u = __builtin_bit_cast(u32, cf);
  u32 s = u>>31;
  int e = (int)((u>>23)&0xFF);
  u32 m = u & 0x7FFFFF;
  int ee = e - 120;                    // target e4m3 exponent field
  if (ee <= 0) return s<<7;            // flush subnormals (|f| < 2^-6) to 0
  u32 m3 = m >> 20, rem = m & 0xFFFFF;
  u32 rnd = (rem > 0x80000u) || (rem == 0x80000u && (m3 & 1));
  m3 += rnd;
  if (m3 == 8){ m3 = 0; ee += 1; }
  if (ee >= 16){ ee = 15; m3 = 6; }    // clamp to 448 (e=15,m=7 is NaN)
  return (s<<7) | ((u32)ee<<3) | m3;
}
__device__ __forceinline__ void fp8x2_to_f32(u32 v, float& a, float& b){
#if __has_builtin(__builtin_amdgcn_cvt_pk_f32_fp8)
  f32x2 r = __builtin_amdgcn_cvt_pk_f32_fp8((int)v, false);
  a = r[0]; b = r[1];
#else
  a = fp8_manual(v & 0xFF); b = fp8_manual((v>>8)&0xFF);
#endif
}
__device__ __forceinline__ u32 f32_to_fp8(float f){
#if __has_builtin(__builtin_amdgcn_cvt_pk_fp8_f32)
  return (u32)__builtin_amdgcn_cvt_pk_fp8_f32(f, 0.f, 0, false) & 0xFF;
#else
  return f32_to_fp8_manual(f);
#endif
}

// ---------------- dtype detector ----------------
__global__ void k_detect(const u32* __restrict__ xw, int* __restrict__ flag){
  __shared__ int votes;
  if (threadIdx.x == 0) votes = 0;
  __syncthreads();
  u32 w = xw[threadIdx.x];
  int e = (w >> 7) & 0xFF;
  if (e >= 100 && e <= 129) atomicAdd(&votes, 1);
  __syncthreads();
  if (threadIdx.x == 0) flag[0] = (votes >= 192) ? 1 : 0;
}

// ---------------- quantize x -> fp8 gather copy ----------------
__global__ void k_quant(const void* __restrict__ src, u8* __restrict__ dstq,
                        const int* __restrict__ flagp){
  int i = blockIdx.x*256 + threadIdx.x;       // element-quad index
  if (i >= NN*HD/4) return;
  int isbf = flagp[0];
  float v0,v1,v2,v3;
  if (isbf){
    u32 a = ((const u32*)src)[i*2+0], b = ((const u32*)src)[i*2+1];
    v0=bflo(a); v1=bfhi(a); v2=bflo(b); v3=bfhi(b);
  } else {
    float4 f = ((const float4*)src)[i];
    v0=f.x; v1=f.y; v2=f.z; v3=f.w;
  }
  u32 q = f32_to_fp8(v0) | (f32_to_fp8(v1)<<8) | (f32_to_fp8(v2)<<16) | (f32_to_fp8(v3)<<24);
  ((u32*)dstq)[i] = q;
}

// ---------------- CSR build (REL-MAJOR: seg = rel*NN + dst) ----------------

__global__ void k_hist(const int* __restrict__ dst, const int* __restrict__ et,
                       int* __restrict__ cnt){
  int e = blockIdx.x*256 + threadIdx.x;
  if (e < EE) atomicAdd(&cnt[et[e]*NN + dst[e]], 1);
}

__global__ void k_scan1(const int* __restrict__ cnt, int* __restrict__ off,
                        int* __restrict__ bsum){
  __shared__ int sh[256];
  int tid = threadIdx.x;
  int i = blockIdx.x*256 + tid;
  int v = (i < NRSEG) ? cnt[i] : 0;
  sh[tid] = v; __syncthreads();
  for (int d=1; d<256; d<<=1){
    int t = (tid >= d) ? sh[tid-d] : 0;
    __syncthreads();
    sh[tid] += t;
    __syncthreads();
  }
  if (i < NRSEG) off[i] = sh[tid] - v;
  if (tid == 255) bsum[blockIdx.x] = sh[255];
}

__global__ __launch_bounds__(1024) void k_scan2(int* __restrict__ bsum, int nb){
  __shared__ int sh[1024];
  __shared__ int carry;
  int tid = threadIdx.x;
  if (tid == 0) carry = 0;
  __syncthreads();
  for (int base=0; base<nb; base+=1024){
    int i = base + tid;
    int v = (i < nb) ? bsum[i] : 0;
    int orig = v;
    sh[tid] = v; __syncthreads();
    for (int d=1; d<1024; d<<=1){
      int t = (tid >= d) ? sh[tid-d] : 0;
      __syncthreads();
      sh[tid] += t;
      __syncthreads();
    }
    int total = sh[1023];
    int excl = sh[tid] - orig + carry;
    if (i < nb) bsum[i] = excl;
    __syncthreads();
    if (tid == 0) carry += total;
    __syncthreads();
  }
}

__global__ void k_scan3(const int* __restrict__ cnt, int* __restrict__ off,
                        const int* __restrict__ bsum){
  int i = blockIdx.x*256 + threadIdx.x;
  if (i < NRSEG){
    int o = off[i] + bsum[blockIdx.x];
    off[i] = o;
    if (i == NRSEG-1) off[NRSEG] = o + cnt[i];
  }
}

__global__ void k_scatter(const int* __restrict__ src, const int* __restrict__ dst,
                          const int* __restrict__ et, const int* __restrict__ off,
                          int* __restrict__ cnt, int* __restrict__ esrc){
  int e = blockIdx.x*256 + threadIdx.x;
  if (e < EE){
    int seg = et[e]*NN + dst[e];
    int p = atomicSub(&cnt[seg], 1) - 1;
    esrc[off[seg] + p] = src[e];
  }
}

// ---------------- weights: WT[r][o][i] = sum_b comp[r,b]*bases[b][i][o]; WT[16]=root^T ----

__global__ void k_weights(const void* __restrict__ bases, const void* __restrict__ comp,
                          const void* __restrict__ root, u16* __restrict__ WT,
                          const int* __restrict__ flagp){
  int idx = blockIdx.x*256 + threadIdx.x;
  if (idx >= 17*16384) return;
  int isbf = flagp[0];
  int r = idx >> 14;
  int o = (idx >> 7) & 127;
  int i = idx & 127;
  float v;
  if (r < RR){
    v = 0.f;
    #pragma unroll
    for (int b=0;b<NBASE;b++)
      v += ldf(comp, r*NBASE+b, isbf) * ldf(bases, (b*FINF + i)*HD + o, isbf);
  } else {
    v = ldf(root, i*HD + o, isbf);
  }
  WT[idx] = f2bf(v);
}

// ---------------- fused aggregate + GEMM layer (v6: all-fp8 input) ----------------
// R6 wave-uniform contiguous-span walk; gathered payload AND root row are fp8
// e4m3 (row = 128 B). Dequant -> fp32 sums -> bf16 A-tile; B bf16 in LDS; MFMA
// unchanged. Output: fp8 copy for next layer (l1,l2) / bf16 for pool (l3).

#define TN 64

__global__ __launch_bounds__(256) void k_layer(
    const u8*  __restrict__ xq,            // fp8 input (gather + root)
    const u16* __restrict__ WT,
    const void* __restrict__ bias, const int* __restrict__ off,
    const int* __restrict__ esrc,
    u16* __restrict__ hout,                // bf16 out (written iff write_bf)
    u8* __restrict__ hq,                   // fp8 out (written iff relu)
    const int* __restrict__ flagp, int write_bf, int relu)
{
  __shared__ __align__(16) u16 Abuf[TN*136];
  __shared__ __align__(16) u16 Bbuf[128*136];
  int tid = threadIdx.x;
  int n0 = blockIdx.x * TN;
  int isbf_in = flagp[0];

  int wv = tid >> 6;
  int lane = tid & 63;
  int mrow = lane & 15;
  int quad = lane >> 4;
  int nwbase = n0 + wv*16;          // wave's first node

  f32x4 acc[8];
  #pragma unroll
  for (int c=0;c<8;c++){ f32x4 z = {0.f,0.f,0.f,0.f}; acc[c] = z; }

  for (int rr=0; rr<17; ++rr){
    __syncthreads();   // LDS free from previous iteration's MFMA reads
    // ---- stage B = WT[rr], padded stride 136 (256 thr x 128 B = 32 KB) ----
    {
      int brow = tid >> 1;
      int bh = tid & 1;
      const uint4* s = (const uint4*)(WT + rr*16384 + brow*128 + bh*64);
      uint4* d = (uint4*)(Bbuf + brow*136 + bh*64);
      #pragma unroll
      for (int q=0;q<8;q++) d[q] = s[q];
    }
    // ---- build A rows for this wave's 16 nodes ----
    if (rr < RR){
      int offv = 0;
      if (lane <= 16){
        int node = nwbase + lane;
        if (node > NN) node = NN;
        offv = off[rr*NN + node];
      }
      int wstart = __builtin_amdgcn_readlane(offv, 0);
      int wend   = __builtin_amdgcn_readlane(offv, 16);
      float a0 = 0.f, a1 = 0.f;
      int idx = 0;
      int cb  = wstart;
      int nb  = __builtin_amdgcn_readlane(offv, 1);
      u16* abase = Abuf + (wv*16)*136 + lane*2;

      auto flushTo = [&](int elim){
        while (idx < 16 && nb <= elim){
          int cnt = nb - cb;
          float inv = (cnt > 0) ? (1.0f/(float)cnt) : 0.0f;
          *(u32*)(abase + idx*136) = pack2(a0*inv, a1*inv);
          a0 = 0.f; a1 = 0.f;
          cb = nb; idx++;
          if (idx < 16) nb = __builtin_amdgcn_readlane(offv, idx+1);
        }
      };

      int e = wstart;
      for (; e + 16 <= wend; e += 16){
        int s[16];
        #pragma unroll
        for (int j=0;j<16;j++) s[j] = esrc[e+j];
        u32 w8[16];
        #pragma unroll
        for (int j=0;j<16;j++) w8[j] = (u32)(*(const u16*)(xq + (size_t)s[j]*HD + lane*2));
        #pragma unroll
        for (int j=0;j<16;j++){
          flushTo(e+j);
          float da, db; fp8x2_to_f32(w8[j], da, db);
          a0 += da; a1 += db;
        }
      }
      for (; e < wend; ++e){
        int s0 = esrc[e];
        u32 w = (u32)(*(const u16*)(xq + (size_t)s0*HD + lane*2));
        flushTo(e);
        float da, db; fp8x2_to_f32(w, da, db);
        a0 += da; a1 += db;
      }
      flushTo(0x7fffffff);    // flush all remaining (incl. empty) segments
    } else {
      // root pass: A row = xq[node] (fp8), coalesced u16/lane
      #pragma unroll 4
      for (int i=0;i<16;i++){
        int node = nwbase + i;
        u32 pv = 0;
        if (node < NN){
          u32 w = (u32)(*(const u16*)(xq + (size_t)node*HD + lane*2));
          float da, db; fp8x2_to_f32(w, da, db);
          pv = pack2(da, db);
        }
        *(u32*)(Abuf + (wv*16 + i)*136 + lane*2) = pv;
      }
    }
    __syncthreads();
    // ---- MFMA: C[64x128] += A[64x128] @ W[rr][128x128] ----
    short8 af[4];
    #pragma unroll
    for (int ks=0;ks<4;ks++)
      af[ks] = *(const short8*)(Abuf + (wv*16 + mrow)*136 + ks*32 + quad*8);
    #pragma unroll
    for (int c=0;c<8;c++){
      #pragma unroll
      for (int ks=0;ks<4;ks++){
        short8 bf = *(const short8*)(Bbuf + (c*16 + mrow)*136 + ks*32 + quad*8);
        acc[c] = __builtin_amdgcn_mfma_f32_16x16x32_bf16(af[ks], bf, acc[c], 0, 0, 0);
      }
    }
  }
  // epilogue: bias (+relu), NaN firewall, store fp8 (next layer) / bf16 (pool)
  #pragma unroll
  for (int c=0;c<8;c++){
    int col = c*16 + mrow;
    float bv = ldf(bias, col, isbf_in);
    #pragma unroll
    for (int rg=0;rg<4;rg++){
      int row = wv*16 + quad*4 + rg;
      int n = n0 + row;
      if (n < NN){
        float v = acc[c][rg] + bv;
        if (relu) v = fmaxf(v, 0.f);
        if (!(v == v)) v = 0.f;
        if (write_bf) hout[(size_t)n*HD + col] = f2bf(v);
        if (relu)     hq[(size_t)n*HD + col] = (u8)f32_to_fp8(v);
      }
    }
  }
}

// ---------------- global mean pool + concat + linear head ----------------

__global__ __launch_bounds__(256) void k_pool_head(
    const u16* __restrict__ h, const int* __restrict__ batch,
    const int* __restrict__ rlab, const void* __restrict__ rel_emb,
    const void* __restrict__ lin_w, const void* __restrict__ lin_b,
    void* __restrict__ out, const int* __restrict__ flagp)
{
  int g = blockIdx.x;
  int isbf = flagp[0];
  __shared__ int bounds[2];
  __shared__ float psum[2][128];
  __shared__ float red[4];
  if (threadIdx.x == 0){
    int lo=0, hi=NN;
    while (lo < hi){ int m=(lo+hi)>>1; if (batch[m] < g) lo=m+1; else hi=m; }
    bounds[0] = lo;
    int lo2=lo, hi2=NN;
    while (lo2 < hi2){ int m=(lo2+hi2)>>1; if (batch[m] < g+1) lo2=m+1; else hi2=m; }
    bounds[1] = lo2;
  }
  __syncthreads();
  int lo = bounds[0], hi = bounds[1];
  int f = threadIdx.x & 127;
  int s = threadIdx.x >> 7;
  float acc = 0.f;
  for (int n = lo + s; n < hi; n += 2) acc += bflo((u32)h[(size_t)n*HD + f]);
  psum[s][f] = acc;
  __syncthreads();
  if (threadIdx.x < 128){
    int cn = hi - lo;
    float pooled = (psum[0][f] + psum[1][f]) / (float)(cn > 0 ? cn : 1);
    int rl = rlab[g];
    float re = ldf(rel_emb, rl*HD + f, isbf);
    float v0 = pooled * ldf(lin_w, f*NCLS+0, isbf) + re * ldf(lin_w, (HD+f)*NCLS+0, isbf);
    float v1 = pooled * ldf(lin_w, f*NCLS+1, isbf) + re * ldf(lin_w, (HD+f)*NCLS+1, isbf);
    #pragma unroll
    for (int o=32;o>0;o>>=1){ v0 += __shfl_down(v0,o); v1 += __shfl_down(v1,o); }
    int ln = threadIdx.x & 63, wvv = threadIdx.x >> 6;
    if (ln == 0){ red[wvv*2] = v0; red[wvv*2+1] = v1; }
  }
  __syncthreads();
  if (threadIdx.x == 0){
    float o0 = red[0] + red[2] + ldf(lin_b, 0, isbf);
    float o1 = red[1] + red[3] + ldf(lin_b, 1, isbf);
    if (isbf){
      ((u16*)out)[g*NCLS+0] = f2bf(o0);
      ((u16*)out)[g*NCLS+1] = f2bf(o1);
    } else {
      ((float*)out)[g*NCLS+0] = o0;
      ((float*)out)[g*NCLS+1] = o1;
    }
  }
}

// ---------------- launch ----------------
// ws budget: proven-good upper bound is 45.37 MB (R3 layout passed end-to-end).
// This layout totals 42.16 MB; cnt (3.2 MB) + bsum (16 KB) alias inside h3
// (h3 is only written by layer 3, long after scatter consumes cnt).

extern "C" void kernel_launch(void* const* d_in, const int* in_sizes, int n_in,
                              void* d_out, int out_size, void* d_ws, size_t ws_size,
                              hipStream_t stream)
{
  (void)in_sizes; (void)n_in; (void)out_size; (void)ws_size;
  const void* x      = d_in[0];
  const int* eidx    = (const int*)d_in[1];
  const int* etype   = (const int*)d_in[2];
  const int* batch   = (const int*)d_in[3];
  const int* rlab    = (const int*)d_in[4];
  const void* rel_emb = d_in[6];
  const void* basesA[3] = {d_in[7],  d_in[11], d_in[15]};
  const void* compA[3]  = {d_in[8],  d_in[12], d_in[16]};
  const void* rootA[3]  = {d_in[9],  d_in[13], d_in[17]};
  const void* biasA[3]  = {d_in[10], d_in[14], d_in[18]};
  const void* lin_w  = d_in[19];
  const void* lin_b  = d_in[20];

  char* p = (char*)d_ws;
  auto alloc = [&](size_t bytes)->char*{ char* r = p; p += (bytes + 255) & ~(size_t)255; return r; };
  int*   flag   = (int*)  alloc(256);
  int*   off    = (int*)  alloc((size_t)(NRSEG+1)*4);
  int*   esrc   = (int*)  alloc((size_t)(EE+64)*4);
  u16*   WT     = (u16*)  alloc((size_t)17*16384*2);
  u8*    xq     = (u8*)   alloc((size_t)NN*HD);
  u8*    h1q    = (u8*)   alloc((size_t)NN*HD);
  u8*    h2q    = (u8*)   alloc((size_t)NN*HD);
  u16*   h3     = (u16*)  alloc((size_t)NN*HD*2);
  // aliases inside h3 (12.8 MB): cnt 3.2 MB @ +0, bsum 16 KB @ +3.2 MB
  int*   cnt    = (int*)h3;
  int*   bsum   = (int*)((char*)h3 + (size_t)NRSEG*4);

  const int* src_in = eidx;        // edge_index[0]
  const int* dst_in = eidx + EE;   // edge_index[1]

  k_detect <<<1, 256, 0, stream>>>((const u32*)x, flag);
  hipMemsetAsync(cnt, 0, (size_t)NRSEG*4, stream);
  k_quant  <<<(NN*HD/4 + 255)/256, 256, 0, stream>>>(x, xq, flag);
  k_hist   <<<EE/256,    256, 0, stream>>>(dst_in, etype, cnt);
  k_scan1  <<<NRSEG/256, 256, 0, stream>>>(cnt, off, bsum);
  k_scan2  <<<1,        1024, 0, stream>>>(bsum, NRSEG/256);
  k_scan3  <<<NRSEG/256, 256, 0, stream>>>(cnt, off, bsum);
  k_scatter<<<EE/256,    256, 0, stream>>>(src_in, dst_in, etype, off, cnt, esrc);

  const int nblk = (NN + TN - 1)/TN;
  // layer 1: in xq -> out h1q (fp8 only)
  k_weights<<<1088, 256, 0, stream>>>(basesA[0], compA[0], rootA[0], WT, flag);
  k_layer<<<nblk, 256, 0, stream>>>(xq,  WT, biasA[0], off, esrc, h3, h1q, flag, 0, 1);
  // layer 2: in h1q -> out h2q (fp8 only)
  k_weights<<<1088, 256, 0, stream>>>(basesA[1], compA[1], rootA[1], WT, flag);
  k_layer<<<nblk, 256, 0, stream>>>(h1q, WT, biasA[1], off, esrc, h3, h2q, flag, 0, 1);
  // layer 3: in h2q -> out h3 (bf16, no relu, no fp8)
  k_weights<<<1088, 256, 0, stream>>>(basesA[2], compA[2], rootA[2], WT, flag);
  k_layer<<<nblk, 256, 0, stream>>>(h2q, WT, biasA[2], off, esrc, h3, h1q, flag, 1, 0);

  k_pool_head<<<NG, 256, 0, stream>>>(h3, batch, rlab, rel_emb, lin_w, lin_b,
                                      d_out, flag);
}

// Round 11
// 1057.605 us; speedup vs baseline: 1.9352x; 1.1794x over previous
//
#include <hip/hip_runtime.h>

#define NN 50000
#define EE 1600000
#define RR 16
#define NBASE 4
#define FINF 128
#define HD 128
#define NG 64
#define NCLS 2
#define NRSEG (NN*RR)   // 800000

typedef __attribute__((ext_vector_type(8))) short short8;
typedef __attribute__((ext_vector_type(4))) float f32x4;
typedef unsigned short u16;
typedef unsigned int u32;
typedef unsigned char u8;

__device__ __forceinline__ float bflo(u32 u){ return __builtin_bit_cast(float, u << 16); }
__device__ __forceinline__ float bfhi(u32 u){ return __builtin_bit_cast(float, u & 0xFFFF0000u); }
__device__ __forceinline__ u16 f2bf(float f){
  u32 u = __builtin_bit_cast(u32, f);
  u += 0x7FFFu + ((u >> 16) & 1u);
  return (u16)(u >> 16);
}
__device__ __forceinline__ u32 pack2(float a, float b){
  return (u32)f2bf(a) | ((u32)f2bf(b) << 16);
}
__device__ __forceinline__ float ldf(const void* p, int i, int isbf){
  return isbf ? bflo((u32)((const u16*)p)[i]) : ((const float*)p)[i];
}

// ---------------- dtype detector ----------------
__global__ void k_detect(const u32* __restrict__ xw, int* __restrict__ flag){
  __shared__ int votes;
  if (threadIdx.x == 0) votes = 0;
  __syncthreads();
  u32 w = xw[threadIdx.x];
  int e = (w >> 7) & 0xFF;
  if (e >= 100 && e <= 129) atomicAdd(&votes, 1);
  __syncthreads();
  if (threadIdx.x == 0) flag[0] = (votes >= 192) ? 1 : 0;
}

// ---------------- CSR build (REL-MAJOR: seg = rel*NN + dst) ----------------

__global__ void k_hist(const int* __restrict__ dst, const int* __restrict__ et,
                       int* __restrict__ cnt){
  int e = blockIdx.x*256 + threadIdx.x;
  if (e < EE) atomicAdd(&cnt[et[e]*NN + dst[e]], 1);
}

__global__ void k_scan1(const int* __restrict__ cnt, int* __restrict__ off,
                        int* __restrict__ bsum){
  __shared__ int sh[256];
  int tid = threadIdx.x;
  int i = blockIdx.x*256 + tid;
  int v = (i < NRSEG) ? cnt[i] : 0;
  sh[tid] = v; __syncthreads();
  for (int d=1; d<256; d<<=1){
    int t = (tid >= d) ? sh[tid-d] : 0;
    __syncthreads();
    sh[tid] += t;
    __syncthreads();
  }
  if (i < NRSEG) off[i] = sh[tid] - v;
  if (tid == 255) bsum[blockIdx.x] = sh[255];
}

__global__ __launch_bounds__(1024) void k_scan2(int* __restrict__ bsum, int nb){
  __shared__ int sh[1024];
  __shared__ int carry;
  int tid = threadIdx.x;
  if (tid == 0) carry = 0;
  __syncthreads();
  for (int base=0; base<nb; base+=1024){
    int i = base + tid;
    int v = (i < nb) ? bsum[i] : 0;
    int orig = v;
    sh[tid] = v; __syncthreads();
    for (int d=1; d<1024; d<<=1){
      int t = (tid >= d) ? sh[tid-d] : 0;
      __syncthreads();
      sh[tid] += t;
      __syncthreads();
    }
    int total = sh[1023];
    int excl = sh[tid] - orig + carry;
    if (i < nb) bsum[i] = excl;
    __syncthreads();
    if (tid == 0) carry += total;
    __syncthreads();
  }
}

__global__ void k_scan3(const int* __restrict__ cnt, int* __restrict__ off,
                        const int* __restrict__ bsum){
  int i = blockIdx.x*256 + threadIdx.x;
  if (i < NRSEG){
    int o = off[i] + bsum[blockIdx.x];
    off[i] = o;
    if (i == NRSEG-1) off[NRSEG] = o + cnt[i];
  }
}

__global__ void k_scatter(const int* __restrict__ src, const int* __restrict__ dst,
                          const int* __restrict__ et, const int* __restrict__ off,
                          int* __restrict__ cnt, int* __restrict__ esrc){
  int e = blockIdx.x*256 + threadIdx.x;
  if (e < EE){
    int seg = et[e]*NN + dst[e];
    int p = atomicSub(&cnt[seg], 1) - 1;
    esrc[off[seg] + p] = src[e];
  }
}

// ---- weights (bf16, FRAGMENT-SWIZZLED): logical WT[r][o][i] stored at
// WTf[((((r*4+wv)*2+ct)*4+ks)*64 + lane)*8 + j] where o=wv*32+ct*16+mrow,
// i=ks*32+quad*8+j, lane=quad*16+mrow. B-frag load = lane*16B contiguous. ----

__global__ void k_weights(const void* __restrict__ bases, const void* __restrict__ comp,
                          const void* __restrict__ root, u16* __restrict__ WTf,
                          const int* __restrict__ flagp){
  int idx = blockIdx.x*256 + threadIdx.x;
  if (idx >= 17*16384) return;
  int isbf = flagp[0];
  int r = idx >> 14;
  int o = (idx >> 7) & 127;
  int i = idx & 127;
  float v;
  if (r < RR){
    v = 0.f;
    #pragma unroll
    for (int b=0;b<NBASE;b++)
      v += ldf(comp, r*NBASE+b, isbf) * ldf(bases, (b*FINF + i)*HD + o, isbf);
  } else {
    v = ldf(root, i*HD + o, isbf);
  }
  int wv = o >> 5, ct = (o >> 4) & 1, mrow = o & 15;
  int ks = i >> 5, quad = (i >> 3) & 3, j = i & 7;
  int lane = quad*16 + mrow;
  WTf[(size_t)((((r*4+wv)*2+ct)*4+ks)*64 + lane)*8 + j] = f2bf(v);
}

// ---------------- fused aggregate + GEMM layer (v8: no B-LDS, TN=32) ----------------
// 32 nodes/block, 256 threads (4 waves). Wave wv gathers nodes [n0+8wv,+8)
// (R6-proven wave-uniform contiguous-span walk, bf16 payload, fp32 sums) and
// computes cols [32wv,+32) over all 32 rows. B-fragments stream from global
// WTf (L2-resident, coalesced 1KB/wave loads). LDS = only A-tile 8.7 KB ->
// occupancy VGPR-limited (~5 blocks/CU vs R8's 3). Numerics identical to R6.

#define TN 32

__global__ __launch_bounds__(256) void k_layer(
    const void* __restrict__ xin,          // bf16 h, or input x (flag dtype)
    const u16* __restrict__ WTf,
    const void* __restrict__ bias, const int* __restrict__ off,
    const int* __restrict__ esrc, u16* __restrict__ hout,
    const int* __restrict__ flagp, int xin_is_input, int relu)
{
  __shared__ __align__(16) u16 Abuf[TN*136];
  int tid = threadIdx.x;
  int n0 = blockIdx.x * TN;
  int isbf_in = flagp[0];
  int isbf_x  = xin_is_input ? isbf_in : 1;

  int wv = tid >> 6;
  int lane = tid & 63;
  int mrow = lane & 15;
  int quad = lane >> 4;
  int nwbase = n0 + wv*8;           // wave's first gather node (8 nodes/wave)

  f32x4 acc[2][2];                  // [mt][ct]
  #pragma unroll
  for (int mt=0;mt<2;mt++)
    #pragma unroll
    for (int ct=0;ct<2;ct++){ f32x4 z = {0.f,0.f,0.f,0.f}; acc[mt][ct] = z; }

  for (int rr=0; rr<17; ++rr){
    __syncthreads();   // Abuf free from previous iteration's MFMA reads
    // ---- build A rows (bf16 means from fp32 sums) for this wave's 8 nodes ----
    if (rr < RR){
      int offv = 0;
      if (lane <= 8){
        int node = nwbase + lane;
        if (node > NN) node = NN;
        offv = off[rr*NN + node];
      }
      int wstart = __builtin_amdgcn_readlane(offv, 0);
      int wend   = __builtin_amdgcn_readlane(offv, 8);
      float a0 = 0.f, a1 = 0.f;
      int idx = 0;
      int cb  = wstart;
      int nb  = __builtin_amdgcn_readlane(offv, 1);
      u16* abase = Abuf + (wv*8)*136 + lane*2;

      auto flushTo = [&](int elim){
        while (idx < 8 && nb <= elim){
          int cnt = nb - cb;
          float inv = (cnt > 0) ? (1.0f/(float)cnt) : 0.0f;
          *(u32*)(abase + idx*136) = pack2(a0*inv, a1*inv);
          a0 = 0.f; a1 = 0.f;
          cb = nb; idx++;
          if (idx < 8) nb = __builtin_amdgcn_readlane(offv, idx+1);
        }
      };

      int e = wstart;
      if (isbf_x){
        const u16* xb = (const u16*)xin;
        for (; e + 16 <= wend; e += 16){
          int s[16];
          #pragma unroll
          for (int j=0;j<16;j++) s[j] = esrc[e+j];
          u32 w[16];
          #pragma unroll
          for (int j=0;j<16;j++) w[j] = *(const u32*)(xb + (size_t)s[j]*HD + lane*2);
          #pragma unroll
          for (int j=0;j<16;j++){
            flushTo(e+j);
            a0 += bflo(w[j]); a1 += bfhi(w[j]);
          }
        }
        for (; e < wend; ++e){
          int s0 = esrc[e];
          u32 w = *(const u32*)(xb + (size_t)s0*HD + lane*2);
          flushTo(e);
          a0 += bflo(w); a1 += bfhi(w);
        }
      } else {
        const float* xb = (const float*)xin;
        for (; e + 16 <= wend; e += 16){
          int s[16];
          #pragma unroll
          for (int j=0;j<16;j++) s[j] = esrc[e+j];
          float2 w[16];
          #pragma unroll
          for (int j=0;j<16;j++) w[j] = *(const float2*)(xb + (size_t)s[j]*HD + lane*2);
          #pragma unroll
          for (int j=0;j<16;j++){
            flushTo(e+j);
            a0 += w[j].x; a1 += w[j].y;
          }
        }
        for (; e < wend; ++e){
          int s0 = esrc[e];
          float2 w = *(const float2*)(xb + (size_t)s0*HD + lane*2);
          flushTo(e);
          a0 += w.x; a1 += w.y;
        }
      }
      flushTo(0x7fffffff);
    } else {
      // root pass: A row = xin[node] (full precision), coalesced
      #pragma unroll
      for (int i=0;i<8;i++){
        int node = nwbase + i;
        u32 pv = 0;
        if (node < NN){
          if (isbf_x){
            pv = *(const u32*)((const u16*)xin + (size_t)node*HD + lane*2);
          } else {
            float2 v = *(const float2*)((const float*)xin + (size_t)node*HD + lane*2);
            pv = pack2(v.x, v.y);
          }
        }
        *(u32*)(Abuf + (wv*8 + i)*136 + lane*2) = pv;
      }
    }
    __syncthreads();
    // ---- B-frags: coalesced global loads from L2-resident swizzled WTf ----
    short8 bfr[2][4];
    {
      const u16* Bp = WTf + (size_t)(((rr*4 + wv)*2)*4*64)*8 + (size_t)lane*8;
      #pragma unroll
      for (int ct=0;ct<2;ct++)
        #pragma unroll
        for (int ks=0;ks<4;ks++)
          bfr[ct][ks] = *(const short8*)(Bp + (size_t)(ct*4 + ks)*64*8);
    }
    // ---- MFMA: C[32 x 32cols(wv)] += A[32x128] @ W[rr] ----
    #pragma unroll
    for (int ks=0;ks<4;ks++){
      short8 af[2];
      #pragma unroll
      for (int mt=0;mt<2;mt++)
        af[mt] = *(const short8*)(Abuf + (mt*16 + mrow)*136 + ks*32 + quad*8);
      #pragma unroll
      for (int ct=0;ct<2;ct++)
        #pragma unroll
        for (int mt=0;mt<2;mt++)
          acc[mt][ct] = __builtin_amdgcn_mfma_f32_16x16x32_bf16(
              af[mt], bfr[ct][ks], acc[mt][ct], 0, 0, 0);
    }
  }
  // epilogue: bias (+relu), NaN firewall, store bf16
  #pragma unroll
  for (int ct=0;ct<2;ct++){
    int col = wv*32 + ct*16 + mrow;
    float bv = ldf(bias, col, isbf_in);
    #pragma unroll
    for (int mt=0;mt<2;mt++){
      #pragma unroll
      for (int rg=0;rg<4;rg++){
        int row = mt*16 + quad*4 + rg;
        int n = n0 + row;
        if (n < NN){
          float v = acc[mt][ct][rg] + bv;
          if (relu) v = fmaxf(v, 0.f);
          if (!(v == v)) v = 0.f;
          hout[(size_t)n*HD + col] = f2bf(v);
        }
      }
    }
  }
}

// ---------------- global mean pool + concat + linear head ----------------

__global__ __launch_bounds__(256) void k_pool_head(
    const u16* __restrict__ h, const int* __restrict__ batch,
    const int* __restrict__ rlab, const void* __restrict__ rel_emb,
    const void* __restrict__ lin_w, const void* __restrict__ lin_b,
    void* __restrict__ out, const int* __restrict__ flagp)
{
  int g = blockIdx.x;
  int isbf = flagp[0];
  __shared__ int bounds[2];
  __shared__ float psum[2][128];
  __shared__ float red[4];
  if (threadIdx.x == 0){
    int lo=0, hi=NN;
    while (lo < hi){ int m=(lo+hi)>>1; if (batch[m] < g) lo=m+1; else hi=m; }
    bounds[0] = lo;
    int lo2=lo, hi2=NN;
    while (lo2 < hi2){ int m=(lo2+hi2)>>1; if (batch[m] < g+1) lo2=m+1; else hi2=m; }
    bounds[1] = lo2;
  }
  __syncthreads();
  int lo = bounds[0], hi = bounds[1];
  int f = threadIdx.x & 127;
  int s = threadIdx.x >> 7;
  float acc = 0.f;
  for (int n = lo + s; n < hi; n += 2) acc += bflo((u32)h[(size_t)n*HD + f]);
  psum[s][f] = acc;
  __syncthreads();
  if (threadIdx.x < 128){
    int cn = hi - lo;
    float pooled = (psum[0][f] + psum[1][f]) / (float)(cn > 0 ? cn : 1);
    int rl = rlab[g];
    float re = ldf(rel_emb, rl*HD + f, isbf);
    float v0 = pooled * ldf(lin_w, f*NCLS+0, isbf) + re * ldf(lin_w, (HD+f)*NCLS+0, isbf);
    float v1 = pooled * ldf(lin_w, f*NCLS+1, isbf) + re * ldf(lin_w, (HD+f)*NCLS+1, isbf);
    #pragma unroll
    for (int o=32;o>0;o>>=1){ v0 += __shfl_down(v0,o); v1 += __shfl_down(v1,o); }
    int ln = threadIdx.x & 63, wvv = threadIdx.x >> 6;
    if (ln == 0){ red[wvv*2] = v0; red[wvv*2+1] = v1; }
  }
  __syncthreads();
  if (threadIdx.x == 0){
    float o0 = red[0] + red[2] + ldf(lin_b, 0, isbf);
    float o1 = red[1] + red[3] + ldf(lin_b, 1, isbf);
    if (isbf){
      ((u16*)out)[g*NCLS+0] = f2bf(o0);
      ((u16*)out)[g*NCLS+1] = f2bf(o1);
    } else {
      ((float*)out)[g*NCLS+0] = o0;
      ((float*)out)[g*NCLS+1] = o1;
    }
  }
}

// ---------------- launch ----------------
// ws total: flag 256B + off 3.2MB + esrc 6.4MB + WTf 544KB + h1 12.8MB +
// h2 12.8MB = 35.8 MB (proven-safe bound: 45.37 MB). Aliases: cnt (3.2MB) +
// bsum inside h1 (dead after scatter, before layer 1 writes); h3 = h1 region
// (h1 dead after layer 2 reads; layer 3 reads h2, writes h3).

extern "C" void kernel_launch(void* const* d_in, const int* in_sizes, int n_in,
                              void* d_out, int out_size, void* d_ws, size_t ws_size,
                              hipStream_t stream)
{
  (void)in_sizes; (void)n_in; (void)out_size; (void)ws_size;
  const void* x      = d_in[0];
  const int* eidx    = (const int*)d_in[1];
  const int* etype   = (const int*)d_in[2];
  const int* batch   = (const int*)d_in[3];
  const int* rlab    = (const int*)d_in[4];
  const void* rel_emb = d_in[6];
  const void* basesA[3] = {d_in[7],  d_in[11], d_in[15]};
  const void* compA[3]  = {d_in[8],  d_in[12], d_in[16]};
  const void* rootA[3]  = {d_in[9],  d_in[13], d_in[17]};
  const void* biasA[3]  = {d_in[10], d_in[14], d_in[18]};
  const void* lin_w  = d_in[19];
  const void* lin_b  = d_in[20];

  char* p = (char*)d_ws;
  auto alloc = [&](size_t bytes)->char*{ char* r = p; p += (bytes + 255) & ~(size_t)255; return r; };
  int*   flag   = (int*)  alloc(256);
  int*   off    = (int*)  alloc((size_t)(NRSEG+1)*4);
  int*   esrc   = (int*)  alloc((size_t)(EE+64)*4);
  u16*   WTf    = (u16*)  alloc((size_t)17*16384*2);
  u16*   h1     = (u16*)  alloc((size_t)NN*HD*2);
  u16*   h2     = (u16*)  alloc((size_t)NN*HD*2);
  // aliases: cnt+bsum inside h1; h3 = h1 region
  int*   cnt    = (int*)h1;
  int*   bsum   = (int*)((char*)h1 + (size_t)NRSEG*4);
  u16*   h3     = h1;

  const int* src_in = eidx;        // edge_index[0]
  const int* dst_in = eidx + EE;   // edge_index[1]

  k_detect <<<1, 256, 0, stream>>>((const u32*)x, flag);
  hipMemsetAsync(cnt, 0, (size_t)NRSEG*4, stream);
  k_hist   <<<EE/256,    256, 0, stream>>>(dst_in, etype, cnt);
  k_scan1  <<<NRSEG/256, 256, 0, stream>>>(cnt, off, bsum);
  k_scan2  <<<1,        1024, 0, stream>>>(bsum, NRSEG/256);
  k_scan3  <<<NRSEG/256, 256, 0, stream>>>(cnt, off, bsum);
  k_scatter<<<EE/256,    256, 0, stream>>>(src_in, dst_in, etype, off, cnt, esrc);

  const int nblk = (NN + TN - 1)/TN;   // 1563
  // layer 1: x -> h1
  k_weights<<<1088, 256, 0, stream>>>(basesA[0], compA[0], rootA[0], WTf, flag);
  k_layer<<<nblk, 256, 0, stream>>>(x,  WTf, biasA[0], off, esrc, h1, flag, 1, 1);
  // layer 2: h1 -> h2
  k_weights<<<1088, 256, 0, stream>>>(basesA[1], compA[1], rootA[1], WTf, flag);
  k_layer<<<nblk, 256, 0, stream>>>(h1, WTf, biasA[1], off, esrc, h2, flag, 0, 1);
  // layer 3: h2 -> h3 (= h1 region, no relu)
  k_weights<<<1088, 256, 0, stream>>>(basesA[2], compA[2], rootA[2], WTf, flag);
  k_layer<<<nblk, 256, 0, stream>>>(h2, WTf, biasA[2], off, esrc, h3, flag, 0, 0);

  k_pool_head<<<NG, 256, 0, stream>>>(h3, batch, rlab, rel_emb, lin_w, lin_b,
                                      d_out, flag);
}

// Round 12
// 932.723 us; speedup vs baseline: 2.1943x; 1.1339x over previous
//
#include <hip/hip_runtime.h>

#define NN 50000
#define EE 1600000
#define RR 16
#define NBASE 4
#define FINF 128
#define HD 128
#define NG 64
#define NCLS 2
#define NRSEG (NN*RR)   // 800000

typedef __attribute__((ext_vector_type(8))) short short8;
typedef __attribute__((ext_vector_type(4))) float f32x4;
typedef __attribute__((ext_vector_type(2))) float f32x2;
typedef unsigned short u16;
typedef unsigned int u32;
typedef unsigned char u8;

__device__ __forceinline__ float bflo(u32 u){ return __builtin_bit_cast(float, u << 16); }
__device__ __forceinline__ float bfhi(u32 u){ return __builtin_bit_cast(float, u & 0xFFFF0000u); }
__device__ __forceinline__ u16 f2bf(float f){
  u32 u = __builtin_bit_cast(u32, f);
  u += 0x7FFFu + ((u >> 16) & 1u);
  return (u16)(u >> 16);
}
__device__ __forceinline__ u32 pack2(float a, float b){
  return (u32)f2bf(a) | ((u32)f2bf(b) << 16);
}
__device__ __forceinline__ float ldf(const void* p, int i, int isbf){
  return isbf ? bflo((u32)((const u16*)p)[i]) : ((const float*)p)[i];
}

// ---------------- fp8 e4m3fn helpers (store paths clamp to +-448) ----------------
__device__ __forceinline__ float fp8_manual(u32 b){
  u32 s = (b>>7)&1, e = (b>>3)&15, m = b&7;
  float v;
  if (e==0) v = (float)m * 0.001953125f;
  else      v = __builtin_bit_cast(float, ((e+120u)<<23) | (m<<20));
  return s ? -v : v;
}
__device__ __forceinline__ u32 f32_to_fp8_manual(float f){
  u32 u = __builtin_bit_cast(u32, f);
  u32 s = u>>31;
  int e = (int)((u>>23)&0xFF);
  u32 m = u & 0x7FFFFF;
  int ee = e - 120;
  if (ee <= 0) return s<<7;
  u32 m3 = m >> 20, rem = m & 0xFFFFF;
  u32 rnd = (rem > 0x80000u) || (rem == 0x80000u && (m3 & 1));
  m3 += rnd;
  if (m3 == 8){ m3 = 0; ee += 1; }
  if (ee >= 16){ ee = 15; m3 = 6; }
  return (s<<7) | ((u32)ee<<3) | m3;
}
__device__ __forceinline__ void fp8x2_to_f32(u32 v, float& a, float& b){
#if __has_builtin(__builtin_amdgcn_cvt_pk_f32_fp8)
  f32x2 r = __builtin_amdgcn_cvt_pk_f32_fp8((int)v, false);
  a = r[0]; b = r[1];
#else
  a = fp8_manual(v & 0xFF); b = fp8_manual((v>>8)&0xFF);
#endif
}
__device__ __forceinline__ u32 pk_fp8x2(float a, float b){
  a = fminf(fmaxf(a, -448.f), 448.f);
  b = fminf(fmaxf(b, -448.f), 448.f);
#if __has_builtin(__builtin_amdgcn_cvt_pk_fp8_f32)
  return (u32)__builtin_amdgcn_cvt_pk_fp8_f32(a, b, 0, false) & 0xFFFF;
#else
  return f32_to_fp8_manual(a) | (f32_to_fp8_manual(b) << 8);
#endif
}

// ---------------- dtype detector ----------------
__global__ void k_detect(const u32* __restrict__ xw, int* __restrict__ flag){
  __shared__ int votes;
  if (threadIdx.x == 0) votes = 0;
  __syncthreads();
  u32 w = xw[threadIdx.x];
  int e = (w >> 7) & 0xFF;
  if (e >= 100 && e <= 129) atomicAdd(&votes, 1);
  __syncthreads();
  if (threadIdx.x == 0) flag[0] = (votes >= 192) ? 1 : 0;
}

// ---------------- quantize x -> fp8 copy ----------------
__global__ void k_quant(const void* __restrict__ src, u8* __restrict__ dstq,
                        const int* __restrict__ flagp){
  int i = blockIdx.x*256 + threadIdx.x;
  if (i >= NN*HD/4) return;
  int isbf = flagp[0];
  float v0,v1,v2,v3;
  if (isbf){
    u32 a = ((const u32*)src)[i*2+0], b = ((const u32*)src)[i*2+1];
    v0=bflo(a); v1=bfhi(a); v2=bflo(b); v3=bfhi(b);
  } else {
    float4 f = ((const float4*)src)[i];
    v0=f.x; v1=f.y; v2=f.z; v3=f.w;
  }
  u32 q = pk_fp8x2(v0,v1) | (pk_fp8x2(v2,v3) << 16);
  ((u32*)dstq)[i] = q;
}

// ---------------- CSR build (REL-MAJOR: seg = rel*NN + dst) ----------------

__global__ void k_hist(const int* __restrict__ dst, const int* __restrict__ et,
                       int* __restrict__ cnt){
  int e = blockIdx.x*256 + threadIdx.x;
  if (e < EE) atomicAdd(&cnt[et[e]*NN + dst[e]], 1);
}

__global__ void k_scan1(const int* __restrict__ cnt, int* __restrict__ off,
                        int* __restrict__ bsum){
  __shared__ int sh[256];
  int tid = threadIdx.x;
  int i = blockIdx.x*256 + tid;
  int v = (i < NRSEG) ? cnt[i] : 0;
  sh[tid] = v; __syncthreads();
  for (int d=1; d<256; d<<=1){
    int t = (tid >= d) ? sh[tid-d] : 0;
    __syncthreads();
    sh[tid] += t;
    __syncthreads();
  }
  if (i < NRSEG) off[i] = sh[tid] - v;
  if (tid == 255) bsum[blockIdx.x] = sh[255];
}

__global__ __launch_bounds__(1024) void k_scan2(int* __restrict__ bsum, int nb){
  __shared__ int sh[1024];
  __shared__ int carry;
  int tid = threadIdx.x;
  if (tid == 0) carry = 0;
  __syncthreads();
  for (int base=0; base<nb; base+=1024){
    int i = base + tid;
    int v = (i < nb) ? bsum[i] : 0;
    int orig = v;
    sh[tid] = v; __syncthreads();
    for (int d=1; d<1024; d<<=1){
      int t = (tid >= d) ? sh[tid-d] : 0;
      __syncthreads();
      sh[tid] += t;
      __syncthreads();
    }
    int total = sh[1023];
    int excl = sh[tid] - orig + carry;
    if (i < nb) bsum[i] = excl;
    __syncthreads();
    if (tid == 0) carry += total;
    __syncthreads();
  }
}

__global__ void k_scan3(const int* __restrict__ cnt, int* __restrict__ off,
                        const int* __restrict__ bsum){
  int i = blockIdx.x*256 + threadIdx.x;
  if (i < NRSEG){
    int o = off[i] + bsum[blockIdx.x];
    off[i] = o;
    if (i == NRSEG-1) off[NRSEG] = o + cnt[i];
  }
}

__global__ void k_scatter(const int* __restrict__ src, const int* __restrict__ dst,
                          const int* __restrict__ et, const int* __restrict__ off,
                          int* __restrict__ cnt, int* __restrict__ esrc){
  int e = blockIdx.x*256 + threadIdx.x;
  if (e < EE){
    int seg = et[e]*NN + dst[e];
    int p = atomicSub(&cnt[seg], 1) - 1;
    esrc[off[seg] + p] = src[e];
  }
}

// ---- weights (bf16, FRAGMENT-SWIZZLED, R11-proven) ----

__global__ void k_weights(const void* __restrict__ bases, const void* __restrict__ comp,
                          const void* __restrict__ root, u16* __restrict__ WTf,
                          const int* __restrict__ flagp){
  int idx = blockIdx.x*256 + threadIdx.x;
  if (idx >= 17*16384) return;
  int isbf = flagp[0];
  int r = idx >> 14;
  int o = (idx >> 7) & 127;
  int i = idx & 127;
  float v;
  if (r < RR){
    v = 0.f;
    #pragma unroll
    for (int b=0;b<NBASE;b++)
      v += ldf(comp, r*NBASE+b, isbf) * ldf(bases, (b*FINF + i)*HD + o, isbf);
  } else {
    v = ldf(root, i*HD + o, isbf);
  }
  int wv = o >> 5, ct = (o >> 4) & 1, mrow = o & 15;
  int ks = i >> 5, quad = (i >> 3) & 3, j = i & 7;
  int lane = quad*16 + mrow;
  WTf[(size_t)((((r*4+wv)*2+ct)*4+ks)*64 + lane)*8 + j] = f2bf(v);
}

// ---------------- fused aggregate + GEMM layer (v9) ----------------
// R11 structure (TN=32, no B-LDS, swizzled WTf) + fp8 activations (gather AND
// root; 6.4MB working set -> L2-resident) + per-block CSR metadata preloaded
// into LDS (off window 16x33; all 16 esrc spans, cap 128 w/ global fallback).
// Per-rr chain collapses to ds_read -> row load. Weights/MFMA stay bf16.

#define TN 32
#define ECAP 128

__global__ __launch_bounds__(256) void k_layer(
    const u8*  __restrict__ xq,            // fp8 input (gather + root)
    const u16* __restrict__ WTf,
    const void* __restrict__ bias, const int* __restrict__ off,
    const int* __restrict__ esrc,
    u16* __restrict__ hout,                // bf16 out (iff write_bf)
    u8* __restrict__ hq,                   // fp8 out (iff !write_bf)
    const int* __restrict__ flagp, int write_bf, int relu)
{
  __shared__ __align__(16) u16 Abuf[TN*136];   // 8704 B (bf16 A tile)
  __shared__ int soff[RR*33];                  // 2112 B
  __shared__ int sesrc[RR*ECAP];               // 8192 B
  int tid = threadIdx.x;
  int n0 = blockIdx.x * TN;
  int isbf_in = flagp[0];

  int wv = tid >> 6;
  int lane = tid & 63;
  int mrow = lane & 15;
  int quad = lane >> 4;
  int nwbase = n0 + wv*8;           // wave's first gather node

  // ---- preload off window: soff[rr][k] = off[rr*NN + min(n0+k,NN)] ----
  for (int i = tid; i < RR*33; i += 256){
    int rr = i / 33, k = i - rr*33;
    int node = n0 + k; if (node > NN) node = NN;
    soff[i] = off[rr*NN + node];
  }
  __syncthreads();
  // ---- stage esrc spans: wave wv stages rr = 4wv..4wv+3 (cap ECAP) ----
  #pragma unroll
  for (int q=0;q<4;q++){
    int rr = wv*4 + q;
    int s0 = soff[rr*33];
    int len = soff[rr*33+32] - s0;
    int lim = len < ECAP ? len : ECAP;
    for (int j = lane; j < lim; j += 64) sesrc[rr*ECAP + j] = esrc[s0 + j];
  }

  f32x4 acc[2][2];                  // [mt][ct]
  #pragma unroll
  for (int mt=0;mt<2;mt++)
    #pragma unroll
    for (int ct=0;ct<2;ct++){ f32x4 z = {0.f,0.f,0.f,0.f}; acc[mt][ct] = z; }

  __syncthreads();   // sesrc ready

  for (int rr=0; rr<17; ++rr){
    // ---- build A rows for this wave's 8 nodes ----
    if (rr < RR){
      int sblk = soff[rr*33];
      int blen = soff[rr*33+32] - sblk;
      int offv = 0;
      if (lane <= 8) offv = soff[rr*33 + wv*8 + lane];
      int wstart = __builtin_amdgcn_readlane(offv, 0);
      int wend   = __builtin_amdgcn_readlane(offv, 8);
      float a0 = 0.f, a1 = 0.f;
      int idx = 0;
      int cb  = wstart;
      int nb  = __builtin_amdgcn_readlane(offv, 1);
      u16* abase = Abuf + (wv*8)*136 + lane*2;

      auto flushTo = [&](int elim){
        while (idx < 8 && nb <= elim){
          int cnt = nb - cb;
          float inv = (cnt > 0) ? (1.0f/(float)cnt) : 0.0f;
          *(u32*)(abase + idx*136) = pack2(a0*inv, a1*inv);
          a0 = 0.f; a1 = 0.f;
          cb = nb; idx++;
          if (idx < 8) nb = __builtin_amdgcn_readlane(offv, idx+1);
        }
      };

      int e = wstart;
      if (blen <= ECAP){
        const int* sp = sesrc + rr*ECAP - sblk;   // sp[e] = staged esrc[e]
        for (; e + 16 <= wend; e += 16){
          int s[16];
          #pragma unroll
          for (int j=0;j<16;j++) s[j] = sp[e+j];
          u32 w[16];
          #pragma unroll
          for (int j=0;j<16;j++) w[j] = (u32)(*(const u16*)(xq + (size_t)s[j]*HD + lane*2));
          #pragma unroll
          for (int j=0;j<16;j++){
            flushTo(e+j);
            float da, db; fp8x2_to_f32(w[j], da, db);
            a0 += da; a1 += db;
          }
        }
        for (; e < wend; ++e){
          int s0 = sp[e];
          u32 w = (u32)(*(const u16*)(xq + (size_t)s0*HD + lane*2));
          flushTo(e);
          float da, db; fp8x2_to_f32(w, da, db);
          a0 += da; a1 += db;
        }
      } else {
        for (; e < wend; ++e){
          int s0 = esrc[e];
          u32 w = (u32)(*(const u16*)(xq + (size_t)s0*HD + lane*2));
          flushTo(e);
          float da, db; fp8x2_to_f32(w, da, db);
          a0 += da; a1 += db;
        }
      }
      flushTo(0x7fffffff);
    } else {
      // root pass: A row = xq[node] (fp8 -> bf16), coalesced u16/lane
      #pragma unroll
      for (int i=0;i<8;i++){
        int node = nwbase + i;
        u32 pv = 0;
        if (node < NN){
          u32 w = (u32)(*(const u16*)(xq + (size_t)node*HD + lane*2));
          float da, db; fp8x2_to_f32(w, da, db);
          pv = pack2(da, db);
        }
        *(u32*)(Abuf + (wv*8 + i)*136 + lane*2) = pv;
      }
    }
    __syncthreads();
    // ---- B-frags: coalesced global loads from L2-resident swizzled WTf ----
    short8 bfr[2][4];
    {
      const u16* Bp = WTf + (size_t)(((rr*4 + wv)*2)*4*64)*8 + (size_t)lane*8;
      #pragma unroll
      for (int ct=0;ct<2;ct++)
        #pragma unroll
        for (int ks=0;ks<4;ks++)
          bfr[ct][ks] = *(const short8*)(Bp + (size_t)(ct*4 + ks)*64*8);
    }
    // ---- MFMA: C[32 x 32cols(wv)] += A[32x128] @ W[rr] ----
    #pragma unroll
    for (int ks=0;ks<4;ks++){
      short8 af[2];
      #pragma unroll
      for (int mt=0;mt<2;mt++)
        af[mt] = *(const short8*)(Abuf + (mt*16 + mrow)*136 + ks*32 + quad*8);
      #pragma unroll
      for (int ct=0;ct<2;ct++)
        #pragma unroll
        for (int mt=0;mt<2;mt++)
          acc[mt][ct] = __builtin_amdgcn_mfma_f32_16x16x32_bf16(
              af[mt], bfr[ct][ks], acc[mt][ct], 0, 0, 0);
    }
    __syncthreads();   // Abuf free for next iteration
  }
  // epilogue: bias (+relu), NaN firewall, store bf16 or clamped fp8
  #pragma unroll
  for (int ct=0;ct<2;ct++){
    int col = wv*32 + ct*16 + mrow;
    float bv = ldf(bias, col, isbf_in);
    #pragma unroll
    for (int mt=0;mt<2;mt++){
      #pragma unroll
      for (int rg=0;rg<4;rg++){
        int row = mt*16 + quad*4 + rg;
        int n = n0 + row;
        if (n < NN){
          float v = acc[mt][ct][rg] + bv;
          if (relu) v = fmaxf(v, 0.f);
          if (!(v == v)) v = 0.f;
          if (write_bf) hout[(size_t)n*HD + col] = f2bf(v);
          else          hq[(size_t)n*HD + col] = (u8)(pk_fp8x2(v, 0.f) & 0xFF);
        }
      }
    }
  }
}

// ---------------- global mean pool (bf16 h) + concat + linear head ----------------

__global__ __launch_bounds__(256) void k_pool_head(
    const u16* __restrict__ h, const int* __restrict__ batch,
    const int* __restrict__ rlab, const void* __restrict__ rel_emb,
    const void* __restrict__ lin_w, const void* __restrict__ lin_b,
    void* __restrict__ out, const int* __restrict__ flagp)
{
  int g = blockIdx.x;
  int isbf = flagp[0];
  __shared__ int bounds[2];
  __shared__ float psum[2][128];
  __shared__ float red[4];
  if (threadIdx.x == 0){
    int lo=0, hi=NN;
    while (lo < hi){ int m=(lo+hi)>>1; if (batch[m] < g) lo=m+1; else hi=m; }
    bounds[0] = lo;
    int lo2=lo, hi2=NN;
    while (lo2 < hi2){ int m=(lo2+hi2)>>1; if (batch[m] < g+1) lo2=m+1; else hi2=m; }
    bounds[1] = lo2;
  }
  __syncthreads();
  int lo = bounds[0], hi = bounds[1];
  int f = threadIdx.x & 127;
  int s = threadIdx.x >> 7;
  float acc = 0.f;
  for (int n = lo + s; n < hi; n += 2) acc += bflo((u32)h[(size_t)n*HD + f]);
  psum[s][f] = acc;
  __syncthreads();
  if (threadIdx.x < 128){
    int cn = hi - lo;
    float pooled = (psum[0][f] + psum[1][f]) / (float)(cn > 0 ? cn : 1);
    int rl = rlab[g];
    float re = ldf(rel_emb, rl*HD + f, isbf);
    float v0 = pooled * ldf(lin_w, f*NCLS+0, isbf) + re * ldf(lin_w, (HD+f)*NCLS+0, isbf);
    float v1 = pooled * ldf(lin_w, f*NCLS+1, isbf) + re * ldf(lin_w, (HD+f)*NCLS+1, isbf);
    #pragma unroll
    for (int o=32;o>0;o>>=1){ v0 += __shfl_down(v0,o); v1 += __shfl_down(v1,o); }
    int ln = threadIdx.x & 63, wvv = threadIdx.x >> 6;
    if (ln == 0){ red[wvv*2] = v0; red[wvv*2+1] = v1; }
  }
  __syncthreads();
  if (threadIdx.x == 0){
    float o0 = red[0] + red[2] + ldf(lin_b, 0, isbf);
    float o1 = red[1] + red[3] + ldf(lin_b, 1, isbf);
    if (isbf){
      ((u16*)out)[g*NCLS+0] = f2bf(o0);
      ((u16*)out)[g*NCLS+1] = f2bf(o1);
    } else {
      ((float*)out)[g*NCLS+0] = o0;
      ((float*)out)[g*NCLS+1] = o1;
    }
  }
}

// ---------------- launch ----------------
// ws: flag 256B + off 3.2MB + esrc 6.4MB + WTf 544KB + xq/h1q/h2q 6.4MB x3 +
// h3 12.8MB = 42.2 MB (< 45.37 proven-safe). cnt+bsum alias inside h3
// (h3 first written by layer 3, after scatter consumes cnt).

extern "C" void kernel_launch(void* const* d_in, const int* in_sizes, int n_in,
                              void* d_out, int out_size, void* d_ws, size_t ws_size,
                              hipStream_t stream)
{
  (void)in_sizes; (void)n_in; (void)out_size; (void)ws_size;
  const void* x      = d_in[0];
  const int* eidx    = (const int*)d_in[1];
  const int* etype   = (const int*)d_in[2];
  const int* batch   = (const int*)d_in[3];
  const int* rlab    = (const int*)d_in[4];
  const void* rel_emb = d_in[6];
  const void* basesA[3] = {d_in[7],  d_in[11], d_in[15]};
  const void* compA[3]  = {d_in[8],  d_in[12], d_in[16]};
  const void* rootA[3]  = {d_in[9],  d_in[13], d_in[17]};
  const void* biasA[3]  = {d_in[10], d_in[14], d_in[18]};
  const void* lin_w  = d_in[19];
  const void* lin_b  = d_in[20];

  char* p = (char*)d_ws;
  auto alloc = [&](size_t bytes)->char*{ char* r = p; p += (bytes + 255) & ~(size_t)255; return r; };
  int*   flag   = (int*)  alloc(256);
  int*   off    = (int*)  alloc((size_t)(NRSEG+1)*4);
  int*   esrc   = (int*)  alloc((size_t)(EE+64)*4);
  u16*   WTf    = (u16*)  alloc((size_t)17*16384*2);
  u8*    xq     = (u8*)   alloc((size_t)NN*HD);
  u8*    h1q    = (u8*)   alloc((size_t)NN*HD);
  u8*    h2q    = (u8*)   alloc((size_t)NN*HD);
  u16*   h3     = (u16*)  alloc((size_t)NN*HD*2);
  // aliases inside h3: cnt 3.2MB @ +0, bsum 16KB after
  int*   cnt    = (int*)h3;
  int*   bsum   = (int*)((char*)h3 + (size_t)NRSEG*4);

  const int* src_in = eidx;        // edge_index[0]
  const int* dst_in = eidx + EE;   // edge_index[1]

  k_detect <<<1, 256, 0, stream>>>((const u32*)x, flag);
  hipMemsetAsync(cnt, 0, (size_t)NRSEG*4, stream);
  k_quant  <<<(NN*HD/4 + 255)/256, 256, 0, stream>>>(x, xq, flag);
  k_hist   <<<EE/256,    256, 0, stream>>>(dst_in, etype, cnt);
  k_scan1  <<<NRSEG/256, 256, 0, stream>>>(cnt, off, bsum);
  k_scan2  <<<1,        1024, 0, stream>>>(bsum, NRSEG/256);
  k_scan3  <<<NRSEG/256, 256, 0, stream>>>(cnt, off, bsum);
  k_scatter<<<EE/256,    256, 0, stream>>>(src_in, dst_in, etype, off, cnt, esrc);

  const int nblk = (NN + TN - 1)/TN;   // 1563
  // layer 1: xq -> h1q (fp8)
  k_weights<<<1088, 256, 0, stream>>>(basesA[0], compA[0], rootA[0], WTf, flag);
  k_layer<<<nblk, 256, 0, stream>>>(xq,  WTf, biasA[0], off, esrc, (u16*)0, h1q, flag, 0, 1);
  // layer 2: h1q -> h2q (fp8)
  k_weights<<<1088, 256, 0, stream>>>(basesA[1], compA[1], rootA[1], WTf, flag);
  k_layer<<<nblk, 256, 0, stream>>>(h1q, WTf, biasA[1], off, esrc, (u16*)0, h2q, flag, 0, 1);
  // layer 3: h2q -> h3 (bf16, no relu)
  k_weights<<<1088, 256, 0, stream>>>(basesA[2], compA[2], rootA[2], WTf, flag);
  k_layer<<<nblk, 256, 0, stream>>>(h2q, WTf, biasA[2], off, esrc, h3, (u8*)0, flag, 1, 0);

  k_pool_head<<<NG, 256, 0, stream>>>(h3, batch, rlab, rel_emb, lin_w, lin_b,
                                      d_out, flag);
}

// Round 13
// 803.825 us; speedup vs baseline: 2.5462x; 1.1604x over previous
//
#include <hip/hip_runtime.h>

#define NN 50000
#define EE 1600000
#define RR 16
#define NBASE 4
#define FINF 128
#define HD 128
#define NG 64
#define NCLS 2
#define NRSEG (NN*RR)   // 800000

typedef __attribute__((ext_vector_type(8))) short short8;
typedef __attribute__((ext_vector_type(4))) float f32x4;
typedef __attribute__((ext_vector_type(2))) float f32x2;
typedef unsigned short u16;
typedef unsigned int u32;
typedef unsigned char u8;

__device__ __forceinline__ float bflo(u32 u){ return __builtin_bit_cast(float, u << 16); }
__device__ __forceinline__ float bfhi(u32 u){ return __builtin_bit_cast(float, u & 0xFFFF0000u); }
__device__ __forceinline__ u16 f2bf(float f){
  u32 u = __builtin_bit_cast(u32, f);
  u += 0x7FFFu + ((u >> 16) & 1u);
  return (u16)(u >> 16);
}
__device__ __forceinline__ u32 pack2(float a, float b){
  return (u32)f2bf(a) | ((u32)f2bf(b) << 16);
}
__device__ __forceinline__ float ldf(const void* p, int i, int isbf){
  return isbf ? bflo((u32)((const u16*)p)[i]) : ((const float*)p)[i];
}

// ---------------- fp8 e4m3fn helpers (store paths clamp to +-448) ----------------
__device__ __forceinline__ float fp8_manual(u32 b){
  u32 s = (b>>7)&1, e = (b>>3)&15, m = b&7;
  float v;
  if (e==0) v = (float)m * 0.001953125f;
  else      v = __builtin_bit_cast(float, ((e+120u)<<23) | (m<<20));
  return s ? -v : v;
}
__device__ __forceinline__ u32 f32_to_fp8_manual(float f){
  u32 u = __builtin_bit_cast(u32, f);
  u32 s = u>>31;
  int e = (int)((u>>23)&0xFF);
  u32 m = u & 0x7FFFFF;
  int ee = e - 120;
  if (ee <= 0) return s<<7;
  u32 m3 = m >> 20, rem = m & 0xFFFFF;
  u32 rnd = (rem > 0x80000u) || (rem == 0x80000u && (m3 & 1));
  m3 += rnd;
  if (m3 == 8){ m3 = 0; ee += 1; }
  if (ee >= 16){ ee = 15; m3 = 6; }
  return (s<<7) | ((u32)ee<<3) | m3;
}
__device__ __forceinline__ void fp8x2_to_f32(u32 v, float& a, float& b){
#if __has_builtin(__builtin_amdgcn_cvt_pk_f32_fp8)
  f32x2 r = __builtin_amdgcn_cvt_pk_f32_fp8((int)v, false);
  a = r[0]; b = r[1];
#else
  a = fp8_manual(v & 0xFF); b = fp8_manual((v>>8)&0xFF);
#endif
}
__device__ __forceinline__ u32 pk_fp8x2(float a, float b){
  a = fminf(fmaxf(a, -448.f), 448.f);
  b = fminf(fmaxf(b, -448.f), 448.f);
#if __has_builtin(__builtin_amdgcn_cvt_pk_fp8_f32)
  return (u32)__builtin_amdgcn_cvt_pk_fp8_f32(a, b, 0, false) & 0xFFFF;
#else
  return f32_to_fp8_manual(a) | (f32_to_fp8_manual(b) << 8);
#endif
}

// ---------------- dtype detector ----------------
__global__ void k_detect(const u32* __restrict__ xw, int* __restrict__ flag){
  __shared__ int votes;
  if (threadIdx.x == 0) votes = 0;
  __syncthreads();
  u32 w = xw[threadIdx.x];
  int e = (w >> 7) & 0xFF;
  if (e >= 100 && e <= 129) atomicAdd(&votes, 1);
  __syncthreads();
  if (threadIdx.x == 0) flag[0] = (votes >= 192) ? 1 : 0;
}

// ---------------- quantize x -> fp8 copy ----------------
__global__ void k_quant(const void* __restrict__ src, u8* __restrict__ dstq,
                        const int* __restrict__ flagp){
  int i = blockIdx.x*256 + threadIdx.x;
  if (i >= NN*HD/4) return;
  int isbf = flagp[0];
  float v0,v1,v2,v3;
  if (isbf){
    u32 a = ((const u32*)src)[i*2+0], b = ((const u32*)src)[i*2+1];
    v0=bflo(a); v1=bfhi(a); v2=bflo(b); v3=bfhi(b);
  } else {
    float4 f = ((const float4*)src)[i];
    v0=f.x; v1=f.y; v2=f.z; v3=f.w;
  }
  u32 q = pk_fp8x2(v0,v1) | (pk_fp8x2(v2,v3) << 16);
  ((u32*)dstq)[i] = q;
}

// ---------------- CSR build (REL-MAJOR: seg = rel*NN + dst) ----------------

__global__ void k_hist(const int* __restrict__ dst, const int* __restrict__ et,
                       int* __restrict__ cnt){
  int e = blockIdx.x*256 + threadIdx.x;
  if (e < EE) atomicAdd(&cnt[et[e]*NN + dst[e]], 1);
}

__global__ void k_scan1(const int* __restrict__ cnt, int* __restrict__ off,
                        int* __restrict__ bsum){
  __shared__ int sh[256];
  int tid = threadIdx.x;
  int i = blockIdx.x*256 + tid;
  int v = (i < NRSEG) ? cnt[i] : 0;
  sh[tid] = v; __syncthreads();
  for (int d=1; d<256; d<<=1){
    int t = (tid >= d) ? sh[tid-d] : 0;
    __syncthreads();
    sh[tid] += t;
    __syncthreads();
  }
  if (i < NRSEG) off[i] = sh[tid] - v;
  if (tid == 255) bsum[blockIdx.x] = sh[255];
}

__global__ __launch_bounds__(1024) void k_scan2(int* __restrict__ bsum, int nb){
  __shared__ int sh[1024];
  __shared__ int carry;
  int tid = threadIdx.x;
  if (tid == 0) carry = 0;
  __syncthreads();
  for (int base=0; base<nb; base+=1024){
    int i = base + tid;
    int v = (i < nb) ? bsum[i] : 0;
    int orig = v;
    sh[tid] = v; __syncthreads();
    for (int d=1; d<1024; d<<=1){
      int t = (tid >= d) ? sh[tid-d] : 0;
      __syncthreads();
      sh[tid] += t;
      __syncthreads();
    }
    int total = sh[1023];
    int excl = sh[tid] - orig + carry;
    if (i < nb) bsum[i] = excl;
    __syncthreads();
    if (tid == 0) carry += total;
    __syncthreads();
  }
}

__global__ void k_scan3(const int* __restrict__ cnt, int* __restrict__ off,
                        const int* __restrict__ bsum){
  int i = blockIdx.x*256 + threadIdx.x;
  if (i < NRSEG){
    int o = off[i] + bsum[blockIdx.x];
    off[i] = o;
    if (i == NRSEG-1) off[NRSEG] = o + cnt[i];
  }
}

__global__ void k_scatter(const int* __restrict__ src, const int* __restrict__ dst,
                          const int* __restrict__ et, const int* __restrict__ off,
                          int* __restrict__ cnt, int* __restrict__ esrc){
  int e = blockIdx.x*256 + threadIdx.x;
  if (e < EE){
    int seg = et[e]*NN + dst[e];
    int p = atomicSub(&cnt[seg], 1) - 1;
    esrc[off[seg] + p] = src[e];
  }
}

// ---- weights (bf16, FRAGMENT-SWIZZLED, R11-proven) ----

__global__ void k_weights(const void* __restrict__ bases, const void* __restrict__ comp,
                          const void* __restrict__ root, u16* __restrict__ WTf,
                          const int* __restrict__ flagp){
  int idx = blockIdx.x*256 + threadIdx.x;
  if (idx >= 17*16384) return;
  int isbf = flagp[0];
  int r = idx >> 14;
  int o = (idx >> 7) & 127;
  int i = idx & 127;
  float v;
  if (r < RR){
    v = 0.f;
    #pragma unroll
    for (int b=0;b<NBASE;b++)
      v += ldf(comp, r*NBASE+b, isbf) * ldf(bases, (b*FINF + i)*HD + o, isbf);
  } else {
    v = ldf(root, i*HD + o, isbf);
  }
  int wv = o >> 5, ct = (o >> 4) & 1, mrow = o & 15;
  int ks = i >> 5, quad = (i >> 3) & 3, j = i & 7;
  int lane = quad*16 + mrow;
  WTf[(u32)((((r*4+wv)*2+ct)*4+ks)*64 + lane)*8 + j] = f2bf(v);
}

// ---------------- fused aggregate + GEMM layer (v10) ----------------
// R12 structure + (1) fully-pipelined predicated gather chunks (16 loads
// always in flight; OOB lanes clamp to a valid staged edge, masked at
// accumulate), (2) 32-bit offsets everywhere, (3) B-fragments prefetched at
// loop top so they overlap the gather phase.

#define TN 32
#define ECAP 128

__global__ __launch_bounds__(256) void k_layer(
    const u8*  __restrict__ xq,            // fp8 input (gather + root)
    const u16* __restrict__ WTf,
    const void* __restrict__ bias, const int* __restrict__ off,
    const int* __restrict__ esrc,
    u16* __restrict__ hout,                // bf16 out (iff write_bf)
    u8* __restrict__ hq,                   // fp8 out (iff !write_bf)
    const int* __restrict__ flagp, int write_bf, int relu)
{
  __shared__ __align__(16) u16 Abuf[TN*136];   // 8704 B
  __shared__ int soff[RR*33];                  // 2112 B
  __shared__ int sesrc[RR*ECAP];               // 8192 B
  int tid = threadIdx.x;
  int n0 = blockIdx.x * TN;
  int isbf_in = flagp[0];

  int wv = tid >> 6;
  int lane = tid & 63;
  int mrow = lane & 15;
  int quad = lane >> 4;
  int nwbase = n0 + wv*8;

  for (int i = tid; i < RR*33; i += 256){
    int rr = i / 33, k = i - rr*33;
    int node = n0 + k; if (node > NN) node = NN;
    soff[i] = off[rr*NN + node];
  }
  __syncthreads();
  #pragma unroll
  for (int q=0;q<4;q++){
    int rr = wv*4 + q;
    int s0 = soff[rr*33];
    int len = soff[rr*33+32] - s0;
    int lim = len < ECAP ? len : ECAP;
    for (int j = lane; j < lim; j += 64) sesrc[rr*ECAP + j] = esrc[s0 + j];
  }

  f32x4 acc[2][2];                  // [mt][ct]
  #pragma unroll
  for (int mt=0;mt<2;mt++)
    #pragma unroll
    for (int ct=0;ct<2;ct++){ f32x4 z = {0.f,0.f,0.f,0.f}; acc[mt][ct] = z; }

  __syncthreads();

  for (int rr=0; rr<17; ++rr){
    // ---- B-frags first: in flight during the entire gather phase ----
    short8 bfr[2][4];
    {
      const u16* Bp = WTf + (u32)(((rr*4 + wv)*2)*4*64)*8 + (u32)lane*8;
      #pragma unroll
      for (int ct=0;ct<2;ct++)
        #pragma unroll
        for (int ks=0;ks<4;ks++)
          bfr[ct][ks] = *(const short8*)(Bp + (u32)(ct*4 + ks)*64*8);
    }
    // ---- build A rows for this wave's 8 nodes ----
    if (rr < RR){
      int sblk = soff[rr*33];
      int blen = soff[rr*33+32] - sblk;
      int offv = 0;
      if (lane <= 8) offv = soff[rr*33 + wv*8 + lane];
      int wstart = __builtin_amdgcn_readlane(offv, 0);
      int wend   = __builtin_amdgcn_readlane(offv, 8);
      float a0 = 0.f, a1 = 0.f;
      int idx = 0;
      int cb  = wstart;
      int nb  = __builtin_amdgcn_readlane(offv, 1);
      u16* abase = Abuf + (wv*8)*136 + lane*2;

      auto flushTo = [&](int elim){
        while (idx < 8 && nb <= elim){
          int cnt = nb - cb;
          float inv = (cnt > 0) ? (1.0f/(float)cnt) : 0.0f;
          *(u32*)(abase + idx*136) = pack2(a0*inv, a1*inv);
          a0 = 0.f; a1 = 0.f;
          cb = nb; idx++;
          if (idx < 8) nb = __builtin_amdgcn_readlane(offv, idx+1);
        }
      };

      if (blen <= ECAP){
        const int* sp = sesrc + rr*ECAP;       // staged span, index by (e - sblk)
        for (int e0i = wstart; e0i < wend; e0i += 16){
          int s8[16];
          #pragma unroll
          for (int j=0;j<16;j++){
            int ee = e0i + j;
            int ec = ee < wend ? ee : (wend - 1);
            s8[j] = sp[ec - sblk];
          }
          u32 w8[16];
          #pragma unroll
          for (int j=0;j<16;j++)
            w8[j] = (u32)(*(const u16*)(xq + (u32)s8[j]*HD + (u32)lane*2));
          #pragma unroll
          for (int j=0;j<16;j++){
            int ee = e0i + j;
            if (ee < wend){
              flushTo(ee);
              float da, db; fp8x2_to_f32(w8[j], da, db);
              a0 += da; a1 += db;
            }
          }
        }
      } else {
        for (int e0i = wstart; e0i < wend; e0i += 16){
          int s8[16];
          #pragma unroll
          for (int j=0;j<16;j++){
            int ee = e0i + j;
            int ec = ee < wend ? ee : (wend - 1);
            s8[j] = esrc[ec];
          }
          u32 w8[16];
          #pragma unroll
          for (int j=0;j<16;j++)
            w8[j] = (u32)(*(const u16*)(xq + (u32)s8[j]*HD + (u32)lane*2));
          #pragma unroll
          for (int j=0;j<16;j++){
            int ee = e0i + j;
            if (ee < wend){
              flushTo(ee);
              float da, db; fp8x2_to_f32(w8[j], da, db);
              a0 += da; a1 += db;
            }
          }
        }
      }
      flushTo(0x7fffffff);
    } else {
      // root pass: A row = xq[node] (fp8 -> bf16), coalesced u16/lane
      #pragma unroll
      for (int i=0;i<8;i++){
        int node = nwbase + i;
        u32 pv = 0;
        if (node < NN){
          u32 w = (u32)(*(const u16*)(xq + (u32)node*HD + (u32)lane*2));
          float da, db; fp8x2_to_f32(w, da, db);
          pv = pack2(da, db);
        }
        *(u32*)(Abuf + (wv*8 + i)*136 + lane*2) = pv;
      }
    }
    __syncthreads();
    // ---- MFMA: C[32 x 32cols(wv)] += A[32x128] @ W[rr] ----
    #pragma unroll
    for (int ks=0;ks<4;ks++){
      short8 af[2];
      #pragma unroll
      for (int mt=0;mt<2;mt++)
        af[mt] = *(const short8*)(Abuf + (mt*16 + mrow)*136 + ks*32 + quad*8);
      #pragma unroll
      for (int ct=0;ct<2;ct++)
        #pragma unroll
        for (int mt=0;mt<2;mt++)
          acc[mt][ct] = __builtin_amdgcn_mfma_f32_16x16x32_bf16(
              af[mt], bfr[ct][ks], acc[mt][ct], 0, 0, 0);
    }
    __syncthreads();   // Abuf free for next iteration
  }
  // epilogue: bias (+relu), NaN firewall, store bf16 or clamped fp8
  #pragma unroll
  for (int ct=0;ct<2;ct++){
    int col = wv*32 + ct*16 + mrow;
    float bv = ldf(bias, col, isbf_in);
    #pragma unroll
    for (int mt=0;mt<2;mt++){
      #pragma unroll
      for (int rg=0;rg<4;rg++){
        int row = mt*16 + quad*4 + rg;
        int n = n0 + row;
        if (n < NN){
          float v = acc[mt][ct][rg] + bv;
          if (relu) v = fmaxf(v, 0.f);
          if (!(v == v)) v = 0.f;
          if (write_bf) hout[(u32)(n*HD + col)] = f2bf(v);
          else          hq[(u32)(n*HD + col)] = (u8)(pk_fp8x2(v, 0.f) & 0xFF);
        }
      }
    }
  }
}

// ---------------- global mean pool (bf16 h) + concat + linear head ----------------

__global__ __launch_bounds__(1024) void k_pool_head(
    const u16* __restrict__ h, const int* __restrict__ batch,
    const int* __restrict__ rlab, const void* __restrict__ rel_emb,
    const void* __restrict__ lin_w, const void* __restrict__ lin_b,
    void* __restrict__ out, const int* __restrict__ flagp)
{
  int g = blockIdx.x;
  int isbf = flagp[0];
  __shared__ int bounds[2];
  __shared__ float psum[8][128];
  __shared__ float red[4];
  if (threadIdx.x == 0){
    int lo=0, hi=NN;
    while (lo < hi){ int m=(lo+hi)>>1; if (batch[m] < g) lo=m+1; else hi=m; }
    bounds[0] = lo;
    int lo2=lo, hi2=NN;
    while (lo2 < hi2){ int m=(lo2+hi2)>>1; if (batch[m] < g+1) lo2=m+1; else hi2=m; }
    bounds[1] = lo2;
  }
  __syncthreads();
  int lo = bounds[0], hi = bounds[1];
  int f = threadIdx.x & 127;
  int s = threadIdx.x >> 7;          // 0..7
  float acc = 0.f;
  for (int n = lo + s; n < hi; n += 8) acc += bflo((u32)h[(u32)(n*HD + f)]);
  psum[s][f] = acc;
  __syncthreads();
  if (threadIdx.x < 128){
    int cn = hi - lo;
    float tot = 0.f;
    #pragma unroll
    for (int k=0;k<8;k++) tot += psum[k][f];
    float pooled = tot / (float)(cn > 0 ? cn : 1);
    int rl = rlab[g];
    float re = ldf(rel_emb, rl*HD + f, isbf);
    float v0 = pooled * ldf(lin_w, f*NCLS+0, isbf) + re * ldf(lin_w, (HD+f)*NCLS+0, isbf);
    float v1 = pooled * ldf(lin_w, f*NCLS+1, isbf) + re * ldf(lin_w, (HD+f)*NCLS+1, isbf);
    #pragma unroll
    for (int o=32;o>0;o>>=1){ v0 += __shfl_down(v0,o); v1 += __shfl_down(v1,o); }
    int ln = threadIdx.x & 63, wvv = threadIdx.x >> 6;
    if (ln == 0){ red[wvv*2] = v0; red[wvv*2+1] = v1; }
  }
  __syncthreads();
  if (threadIdx.x == 0){
    float o0 = red[0] + red[2] + ldf(lin_b, 0, isbf);
    float o1 = red[1] + red[3] + ldf(lin_b, 1, isbf);
    if (isbf){
      ((u16*)out)[g*NCLS+0] = f2bf(o0);
      ((u16*)out)[g*NCLS+1] = f2bf(o1);
    } else {
      ((float*)out)[g*NCLS+0] = o0;
      ((float*)out)[g*NCLS+1] = o1;
    }
  }
}

// ---------------- launch ----------------
// ws: flag 256B + off 3.2MB + esrc 6.4MB + WTf 544KB + xq/h1q/h2q 6.4MB x3 +
// h3 12.8MB = 42.2 MB (< 45.37 proven-safe). cnt+bsum alias inside h3.

extern "C" void kernel_launch(void* const* d_in, const int* in_sizes, int n_in,
                              void* d_out, int out_size, void* d_ws, size_t ws_size,
                              hipStream_t stream)
{
  (void)in_sizes; (void)n_in; (void)out_size; (void)ws_size;
  const void* x      = d_in[0];
  const int* eidx    = (const int*)d_in[1];
  const int* etype   = (const int*)d_in[2];
  const int* batch   = (const int*)d_in[3];
  const int* rlab    = (const int*)d_in[4];
  const void* rel_emb = d_in[6];
  const void* basesA[3] = {d_in[7],  d_in[11], d_in[15]};
  const void* compA[3]  = {d_in[8],  d_in[12], d_in[16]};
  const void* rootA[3]  = {d_in[9],  d_in[13], d_in[17]};
  const void* biasA[3]  = {d_in[10], d_in[14], d_in[18]};
  const void* lin_w  = d_in[19];
  const void* lin_b  = d_in[20];

  char* p = (char*)d_ws;
  auto alloc = [&](size_t bytes)->char*{ char* r = p; p += (bytes + 255) & ~(size_t)255; return r; };
  int*   flag   = (int*)  alloc(256);
  int*   off    = (int*)  alloc((size_t)(NRSEG+1)*4);
  int*   esrc   = (int*)  alloc((size_t)(EE+64)*4);
  u16*   WTf    = (u16*)  alloc((size_t)17*16384*2);
  u8*    xq     = (u8*)   alloc((size_t)NN*HD);
  u8*    h1q    = (u8*)   alloc((size_t)NN*HD);
  u8*    h2q    = (u8*)   alloc((size_t)NN*HD);
  u16*   h3     = (u16*)  alloc((size_t)NN*HD*2);
  int*   cnt    = (int*)h3;
  int*   bsum   = (int*)((char*)h3 + (size_t)NRSEG*4);

  const int* src_in = eidx;        // edge_index[0]
  const int* dst_in = eidx + EE;   // edge_index[1]

  k_detect <<<1, 256, 0, stream>>>((const u32*)x, flag);
  hipMemsetAsync(cnt, 0, (size_t)NRSEG*4, stream);
  k_quant  <<<(NN*HD/4 + 255)/256, 256, 0, stream>>>(x, xq, flag);
  k_hist   <<<EE/256,    256, 0, stream>>>(dst_in, etype, cnt);
  k_scan1  <<<NRSEG/256, 256, 0, stream>>>(cnt, off, bsum);
  k_scan2  <<<1,        1024, 0, stream>>>(bsum, NRSEG/256);
  k_scan3  <<<NRSEG/256, 256, 0, stream>>>(cnt, off, bsum);
  k_scatter<<<EE/256,    256, 0, stream>>>(src_in, dst_in, etype, off, cnt, esrc);

  const int nblk = (NN + TN - 1)/TN;   // 1563
  // layer 1: xq -> h1q (fp8)
  k_weights<<<1088, 256, 0, stream>>>(basesA[0], compA[0], rootA[0], WTf, flag);
  k_layer<<<nblk, 256, 0, stream>>>(xq,  WTf, biasA[0], off, esrc, (u16*)0, h1q, flag, 0, 1);
  // layer 2: h1q -> h2q (fp8)
  k_weights<<<1088, 256, 0, stream>>>(basesA[1], compA[1], rootA[1], WTf, flag);
  k_layer<<<nblk, 256, 0, stream>>>(h1q, WTf, biasA[1], off, esrc, (u16*)0, h2q, flag, 0, 1);
  // layer 3: h2q -> h3 (bf16, no relu)
  k_weights<<<1088, 256, 0, stream>>>(basesA[2], compA[2], rootA[2], WTf, flag);
  k_layer<<<nblk, 256, 0, stream>>>(h2q, WTf, biasA[2], off, esrc, h3, (u8*)0, flag, 1, 0);

  k_pool_head<<<NG, 1024, 0, stream>>>(h3, batch, rlab, rel_emb, lin_w, lin_b,
                                       d_out, flag);
}

// Round 14
// 654.259 us; speedup vs baseline: 3.1283x; 1.2286x over previous
//
#include <hip/hip_runtime.h>

#define NN 50000
#define EE 1600000
#define RR 16
#define NBASE 4
#define FINF 128
#define HD 128
#define NG 64
#define NCLS 2
#define NRSEG (NN*RR)   // 800000

typedef __attribute__((ext_vector_type(8))) short short8;
typedef __attribute__((ext_vector_type(4))) float f32x4;
typedef __attribute__((ext_vector_type(2))) float f32x2;
typedef unsigned short u16;
typedef unsigned int u32;
typedef unsigned long long u64;
typedef unsigned char u8;

__device__ __forceinline__ float bflo(u32 u){ return __builtin_bit_cast(float, u << 16); }
__device__ __forceinline__ float bfhi(u32 u){ return __builtin_bit_cast(float, u & 0xFFFF0000u); }
__device__ __forceinline__ u16 f2bf(float f){
  u32 u = __builtin_bit_cast(u32, f);
  u += 0x7FFFu + ((u >> 16) & 1u);
  return (u16)(u >> 16);
}
__device__ __forceinline__ u32 pack2(float a, float b){
  return (u32)f2bf(a) | ((u32)f2bf(b) << 16);
}
__device__ __forceinline__ float ldf(const void* p, int i, int isbf){
  return isbf ? bflo((u32)((const u16*)p)[i]) : ((const float*)p)[i];
}

// ---------------- fp8 e4m3fn helpers (store paths clamp to +-448) ----------------
__device__ __forceinline__ float fp8_manual(u32 b){
  u32 s = (b>>7)&1, e = (b>>3)&15, m = b&7;
  float v;
  if (e==0) v = (float)m * 0.001953125f;
  else      v = __builtin_bit_cast(float, ((e+120u)<<23) | (m<<20));
  return s ? -v : v;
}
__device__ __forceinline__ u32 f32_to_fp8_manual(float f){
  u32 u = __builtin_bit_cast(u32, f);
  u32 s = u>>31;
  int e = (int)((u>>23)&0xFF);
  u32 m = u & 0x7FFFFF;
  int ee = e - 120;
  if (ee <= 0) return s<<7;
  u32 m3 = m >> 20, rem = m & 0xFFFFF;
  u32 rnd = (rem > 0x80000u) || (rem == 0x80000u && (m3 & 1));
  m3 += rnd;
  if (m3 == 8){ m3 = 0; ee += 1; }
  if (ee >= 16){ ee = 15; m3 = 6; }
  return (s<<7) | ((u32)ee<<3) | m3;
}
__device__ __forceinline__ void fp8x2_to_f32(u32 v, float& a, float& b){
#if __has_builtin(__builtin_amdgcn_cvt_pk_f32_fp8)
  f32x2 r = __builtin_amdgcn_cvt_pk_f32_fp8((int)v, false);
  a = r[0]; b = r[1];
#else
  a = fp8_manual(v & 0xFF); b = fp8_manual((v>>8)&0xFF);
#endif
}
__device__ __forceinline__ u32 pk_fp8x2(float a, float b){
  a = fminf(fmaxf(a, -448.f), 448.f);
  b = fminf(fmaxf(b, -448.f), 448.f);
#if __has_builtin(__builtin_amdgcn_cvt_pk_fp8_f32)
  return (u32)__builtin_amdgcn_cvt_pk_fp8_f32(a, b, 0, false) & 0xFFFF;
#else
  return f32_to_fp8_manual(a) | (f32_to_fp8_manual(b) << 8);
#endif
}

// ---------------- dtype detector ----------------
__global__ void k_detect(const u32* __restrict__ xw, int* __restrict__ flag){
  __shared__ int votes;
  if (threadIdx.x == 0) votes = 0;
  __syncthreads();
  u32 w = xw[threadIdx.x];
  int e = (w >> 7) & 0xFF;
  if (e >= 100 && e <= 129) atomicAdd(&votes, 1);
  __syncthreads();
  if (threadIdx.x == 0) flag[0] = (votes >= 192) ? 1 : 0;
}

// ---------------- quantize x -> fp8 copy ----------------
__global__ void k_quant(const void* __restrict__ src, u8* __restrict__ dstq,
                        const int* __restrict__ flagp){
  int i = blockIdx.x*256 + threadIdx.x;
  if (i >= NN*HD/4) return;
  int isbf = flagp[0];
  float v0,v1,v2,v3;
  if (isbf){
    u32 a = ((const u32*)src)[i*2+0], b = ((const u32*)src)[i*2+1];
    v0=bflo(a); v1=bfhi(a); v2=bflo(b); v3=bfhi(b);
  } else {
    float4 f = ((const float4*)src)[i];
    v0=f.x; v1=f.y; v2=f.z; v3=f.w;
  }
  u32 q = pk_fp8x2(v0,v1) | (pk_fp8x2(v2,v3) << 16);
  ((u32*)dstq)[i] = q;
}

// ---------------- CSR build (REL-MAJOR: seg = rel*NN + dst) ----------------

__global__ void k_hist(const int* __restrict__ dst, const int* __restrict__ et,
                       int* __restrict__ cnt){
  int e = blockIdx.x*256 + threadIdx.x;
  if (e < EE) atomicAdd(&cnt[et[e]*NN + dst[e]], 1);
}

__global__ void k_scan1(const int* __restrict__ cnt, int* __restrict__ off,
                        int* __restrict__ bsum){
  __shared__ int sh[256];
  int tid = threadIdx.x;
  int i = blockIdx.x*256 + tid;
  int v = (i < NRSEG) ? cnt[i] : 0;
  sh[tid] = v; __syncthreads();
  for (int d=1; d<256; d<<=1){
    int t = (tid >= d) ? sh[tid-d] : 0;
    __syncthreads();
    sh[tid] += t;
    __syncthreads();
  }
  if (i < NRSEG) off[i] = sh[tid] - v;
  if (tid == 255) bsum[blockIdx.x] = sh[255];
}

__global__ __launch_bounds__(1024) void k_scan2(int* __restrict__ bsum, int nb){
  __shared__ int sh[1024];
  __shared__ int carry;
  int tid = threadIdx.x;
  if (tid == 0) carry = 0;
  __syncthreads();
  for (int base=0; base<nb; base+=1024){
    int i = base + tid;
    int v = (i < nb) ? bsum[i] : 0;
    int orig = v;
    sh[tid] = v; __syncthreads();
    for (int d=1; d<1024; d<<=1){
      int t = (tid >= d) ? sh[tid-d] : 0;
      __syncthreads();
      sh[tid] += t;
      __syncthreads();
    }
    int total = sh[1023];
    int excl = sh[tid] - orig + carry;
    if (i < nb) bsum[i] = excl;
    __syncthreads();
    if (tid == 0) carry += total;
    __syncthreads();
  }
}

__global__ void k_scan3(const int* __restrict__ cnt, int* __restrict__ off,
                        const int* __restrict__ bsum){
  int i = blockIdx.x*256 + threadIdx.x;
  if (i < NRSEG){
    int o = off[i] + bsum[blockIdx.x];
    off[i] = o;
    if (i == NRSEG-1) off[NRSEG] = o + cnt[i];
  }
}

__global__ void k_scatter(const int* __restrict__ src, const int* __restrict__ dst,
                          const int* __restrict__ et, const int* __restrict__ off,
                          int* __restrict__ cnt, int* __restrict__ esrc){
  int e = blockIdx.x*256 + threadIdx.x;
  if (e < EE){
    int seg = et[e]*NN + dst[e];
    int p = atomicSub(&cnt[seg], 1) - 1;
    esrc[off[seg] + p] = src[e];
  }
}

// ---- weights (bf16, FRAGMENT-SWIZZLED, R11-proven) ----

__global__ void k_weights(const void* __restrict__ bases, const void* __restrict__ comp,
                          const void* __restrict__ root, u16* __restrict__ WTf,
                          const int* __restrict__ flagp){
  int idx = blockIdx.x*256 + threadIdx.x;
  if (idx >= 17*16384) return;
  int isbf = flagp[0];
  int r = idx >> 14;
  int o = (idx >> 7) & 127;
  int i = idx & 127;
  float v;
  if (r < RR){
    v = 0.f;
    #pragma unroll
    for (int b=0;b<NBASE;b++)
      v += ldf(comp, r*NBASE+b, isbf) * ldf(bases, (b*FINF + i)*HD + o, isbf);
  } else {
    v = ldf(root, i*HD + o, isbf);
  }
  int wv = o >> 5, ct = (o >> 4) & 1, mrow = o & 15;
  int ks = i >> 5, quad = (i >> 3) & 3, j = i & 7;
  int lane = quad*16 + mrow;
  WTf[(u32)((((r*4+wv)*2+ct)*4+ks)*64 + lane)*8 + j] = f2bf(v);
}

// ---------------- fused aggregate + GEMM layer (v11: wave-per-relation) ----------------
// TN=16 nodes/block, 3125 blocks (no tail), 256 threads (4 waves).
// 4 rounds: in round t, wave wv gathers relation t*4+wv's contiguous span
// (~32 edges, all 16 nodes) into its own A-tile; barrier; all waves MFMA the
// 4 staged relations (wave wv owns cols 32wv..32wv+31); barrier. 9 barriers
// total (vs 34). Root pass barrier-free (A-frags direct from xq).
// LDS 20.5 KB -> 7 blocks/CU; grid supplies 12.2 -> occupancy ~80%.

#define TN 16
#define ECAP 128

__global__ __launch_bounds__(256) void k_layer(
    const u8*  __restrict__ xq,            // fp8 input (gather + root)
    const u16* __restrict__ WTf,
    const void* __restrict__ bias, const int* __restrict__ off,
    const int* __restrict__ esrc,
    u16* __restrict__ hout,                // bf16 out (iff write_bf)
    u8* __restrict__ hq,                   // fp8 out (iff !write_bf)
    const int* __restrict__ flagp, int write_bf, int relu)
{
  __shared__ __align__(16) u16 Abuf[4][TN*136];  // 17408 B
  __shared__ int soff[RR*17];                    // 1088 B
  __shared__ int sesrc[4][ECAP];                 // 2048 B
  int tid = threadIdx.x;
  int n0 = blockIdx.x * TN;
  int isbf_in = flagp[0];

  int wv = tid >> 6;
  int lane = tid & 63;
  int mrow = lane & 15;
  int quad = lane >> 4;

  // ---- stage off window: soff[r*17+k] = off[r*NN + n0 + k], k=0..16 ----
  for (int i = tid; i < RR*17; i += 256){
    int r = i / 17, k = i - r*17;
    soff[i] = off[r*NN + n0 + k];
  }
  __syncthreads();

  f32x4 acc[2];
  { f32x4 z = {0.f,0.f,0.f,0.f}; acc[0] = z; acc[1] = z; }

  for (int t=0; t<4; ++t){
    int r = t*4 + wv;
    // ---- wave-private: stage span + gather 16 nodes into Abuf[wv] ----
    {
      int offv = 0;
      if (lane <= 16) offv = soff[r*17 + lane];
      int wstart = __builtin_amdgcn_readlane(offv, 0);
      int wend   = __builtin_amdgcn_readlane(offv, 16);
      int blen = wend - wstart;
      bool staged = (blen <= ECAP);
      if (staged){
        for (int j = lane; j < blen; j += 64) sesrc[wv][j] = esrc[wstart + j];
      }
      float a0 = 0.f, a1 = 0.f;
      int idx = 0;
      int cb  = wstart;
      int nb  = __builtin_amdgcn_readlane(offv, 1);
      u16* abase = Abuf[wv] + lane*2;

      auto flushTo = [&](int elim){
        while (idx < TN && nb <= elim){
          int cnt = nb - cb;
          float inv = (cnt > 0) ? (1.0f/(float)cnt) : 0.0f;
          *(u32*)(abase + idx*136) = pack2(a0*inv, a1*inv);
          a0 = 0.f; a1 = 0.f;
          cb = nb; idx++;
          if (idx < TN) nb = __builtin_amdgcn_readlane(offv, idx+1);
        }
      };

      if (staged){
        const int* sp = sesrc[wv];             // index by (e - wstart)
        for (int e0i = wstart; e0i < wend; e0i += 16){
          int s8[16];
          #pragma unroll
          for (int j=0;j<16;j++){
            int ee = e0i + j;
            int ec = ee < wend ? ee : (wend - 1);
            s8[j] = sp[ec - wstart];
          }
          u32 w8[16];
          #pragma unroll
          for (int j=0;j<16;j++)
            w8[j] = (u32)(*(const u16*)(xq + (u32)s8[j]*HD + (u32)lane*2));
          #pragma unroll
          for (int j=0;j<16;j++){
            int ee = e0i + j;
            if (ee < wend){
              flushTo(ee);
              float da, db; fp8x2_to_f32(w8[j], da, db);
              a0 += da; a1 += db;
            }
          }
        }
      } else {
        for (int e0i = wstart; e0i < wend; e0i += 16){
          int s8[16];
          #pragma unroll
          for (int j=0;j<16;j++){
            int ee = e0i + j;
            int ec = ee < wend ? ee : (wend - 1);
            s8[j] = esrc[ec];
          }
          u32 w8[16];
          #pragma unroll
          for (int j=0;j<16;j++)
            w8[j] = (u32)(*(const u16*)(xq + (u32)s8[j]*HD + (u32)lane*2));
          #pragma unroll
          for (int j=0;j<16;j++){
            int ee = e0i + j;
            if (ee < wend){
              flushTo(ee);
              float da, db; fp8x2_to_f32(w8[j], da, db);
              a0 += da; a1 += db;
            }
          }
        }
      }
      flushTo(0x7fffffff);
    }
    __syncthreads();
    // ---- MFMA: 4 staged relations; wave wv owns cols [32wv, 32wv+32) ----
    #pragma unroll
    for (int rloc=0; rloc<4; ++rloc){
      int rr = t*4 + rloc;
      const u16* Bp = WTf + (u32)(((rr*4 + wv)*2)*4*64)*8 + (u32)lane*8;
      #pragma unroll
      for (int ks=0; ks<4; ++ks){
        short8 af = *(const short8*)(Abuf[rloc] + mrow*136 + ks*32 + quad*8);
        #pragma unroll
        for (int ct=0; ct<2; ++ct){
          short8 bf = *(const short8*)(Bp + (u32)(ct*4 + ks)*64*8);
          acc[ct] = __builtin_amdgcn_mfma_f32_16x16x32_bf16(af, bf, acc[ct], 0, 0, 0);
        }
      }
    }
    __syncthreads();   // A tiles free for next round
  }
  // ---- root pass: barrier-free, A-frags direct from xq (L2-hot 2KB region) ----
  {
    const u8* xrow = xq + (u32)(n0 + mrow)*HD;
    const u16* Bp = WTf + (u32)(((16*4 + wv)*2)*4*64)*8 + (u32)lane*8;
    #pragma unroll
    for (int ks=0; ks<4; ++ks){
      u32 lo = *(const u32*)(xrow + ks*32 + quad*8);
      u32 hi = *(const u32*)(xrow + ks*32 + quad*8 + 4);
      float f0,f1,f2,f3,f4,f5,f6,f7;
      fp8x2_to_f32(lo & 0xFFFFu, f0, f1);
      fp8x2_to_f32(lo >> 16,     f2, f3);
      fp8x2_to_f32(hi & 0xFFFFu, f4, f5);
      fp8x2_to_f32(hi >> 16,     f6, f7);
      union { short8 v; u32 w[4]; } u;
      u.w[0] = pack2(f0,f1); u.w[1] = pack2(f2,f3);
      u.w[2] = pack2(f4,f5); u.w[3] = pack2(f6,f7);
      #pragma unroll
      for (int ct=0; ct<2; ++ct){
        short8 bf = *(const short8*)(Bp + (u32)(ct*4 + ks)*64*8);
        acc[ct] = __builtin_amdgcn_mfma_f32_16x16x32_bf16(u.v, bf, acc[ct], 0, 0, 0);
      }
    }
  }
  // ---- epilogue: node = n0 + quad*4 + rg; col = wv*32 + ct*16 + mrow ----
  #pragma unroll
  for (int ct=0; ct<2; ++ct){
    int col = wv*32 + ct*16 + mrow;
    float bv = ldf(bias, col, isbf_in);
    #pragma unroll
    for (int rg=0; rg<4; ++rg){
      int n = n0 + quad*4 + rg;
      float v = acc[ct][rg] + bv;
      if (relu) v = fmaxf(v, 0.f);
      if (!(v == v)) v = 0.f;
      if (write_bf) hout[(u32)(n*HD + col)] = f2bf(v);
      else          hq[(u32)(n*HD + col)] = (u8)(pk_fp8x2(v, 0.f) & 0xFF);
    }
  }
}

// ---------------- global mean pool (bf16 h) + concat + linear head ----------------

__global__ __launch_bounds__(1024) void k_pool_head(
    const u16* __restrict__ h, const int* __restrict__ batch,
    const int* __restrict__ rlab, const void* __restrict__ rel_emb,
    const void* __restrict__ lin_w, const void* __restrict__ lin_b,
    void* __restrict__ out, const int* __restrict__ flagp)
{
  int g = blockIdx.x;
  int isbf = flagp[0];
  __shared__ int bounds[2];
  __shared__ float psum[8][128];
  __shared__ float red[4];
  if (threadIdx.x == 0){
    int lo=0, hi=NN;
    while (lo < hi){ int m=(lo+hi)>>1; if (batch[m] < g) lo=m+1; else hi=m; }
    bounds[0] = lo;
    int lo2=lo, hi2=NN;
    while (lo2 < hi2){ int m=(lo2+hi2)>>1; if (batch[m] < g+1) lo2=m+1; else hi2=m; }
    bounds[1] = lo2;
  }
  __syncthreads();
  int lo = bounds[0], hi = bounds[1];
  int f = threadIdx.x & 127;
  int s = threadIdx.x >> 7;          // 0..7
  float acc = 0.f;
  for (int n = lo + s; n < hi; n += 8) acc += bflo((u32)h[(u32)(n*HD + f)]);
  psum[s][f] = acc;
  __syncthreads();
  if (threadIdx.x < 128){
    int cn = hi - lo;
    float tot = 0.f;
    #pragma unroll
    for (int k=0;k<8;k++) tot += psum[k][f];
    float pooled = tot / (float)(cn > 0 ? cn : 1);
    int rl = rlab[g];
    float re = ldf(rel_emb, rl*HD + f, isbf);
    float v0 = pooled * ldf(lin_w, f*NCLS+0, isbf) + re * ldf(lin_w, (HD+f)*NCLS+0, isbf);
    float v1 = pooled * ldf(lin_w, f*NCLS+1, isbf) + re * ldf(lin_w, (HD+f)*NCLS+1, isbf);
    #pragma unroll
    for (int o=32;o>0;o>>=1){ v0 += __shfl_down(v0,o); v1 += __shfl_down(v1,o); }
    int ln = threadIdx.x & 63, wvv = threadIdx.x >> 6;
    if (ln == 0){ red[wvv*2] = v0; red[wvv*2+1] = v1; }
  }
  __syncthreads();
  if (threadIdx.x == 0){
    float o0 = red[0] + red[2] + ldf(lin_b, 0, isbf);
    float o1 = red[1] + red[3] + ldf(lin_b, 1, isbf);
    if (isbf){
      ((u16*)out)[g*NCLS+0] = f2bf(o0);
      ((u16*)out)[g*NCLS+1] = f2bf(o1);
    } else {
      ((float*)out)[g*NCLS+0] = o0;
      ((float*)out)[g*NCLS+1] = o1;
    }
  }
}

// ---------------- launch ----------------
// ws: flag 256B + off 3.2MB + esrc 6.4MB + WTf 544KB + xq/h1q/h2q 6.4MB x3 +
// h3 12.8MB = 42.2 MB (< 45.37 proven-safe). cnt+bsum alias inside h3.

extern "C" void kernel_launch(void* const* d_in, const int* in_sizes, int n_in,
                              void* d_out, int out_size, void* d_ws, size_t ws_size,
                              hipStream_t stream)
{
  (void)in_sizes; (void)n_in; (void)out_size; (void)ws_size;
  const void* x      = d_in[0];
  const int* eidx    = (const int*)d_in[1];
  const int* etype   = (const int*)d_in[2];
  const int* batch   = (const int*)d_in[3];
  const int* rlab    = (const int*)d_in[4];
  const void* rel_emb = d_in[6];
  const void* basesA[3] = {d_in[7],  d_in[11], d_in[15]};
  const void* compA[3]  = {d_in[8],  d_in[12], d_in[16]};
  const void* rootA[3]  = {d_in[9],  d_in[13], d_in[17]};
  const void* biasA[3]  = {d_in[10], d_in[14], d_in[18]};
  const void* lin_w  = d_in[19];
  const void* lin_b  = d_in[20];

  char* p = (char*)d_ws;
  auto alloc = [&](size_t bytes)->char*{ char* r = p; p += (bytes + 255) & ~(size_t)255; return r; };
  int*   flag   = (int*)  alloc(256);
  int*   off    = (int*)  alloc((size_t)(NRSEG+1)*4);
  int*   esrc   = (int*)  alloc((size_t)(EE+64)*4);
  u16*   WTf    = (u16*)  alloc((size_t)17*16384*2);
  u8*    xq     = (u8*)   alloc((size_t)NN*HD);
  u8*    h1q    = (u8*)   alloc((size_t)NN*HD);
  u8*    h2q    = (u8*)   alloc((size_t)NN*HD);
  u16*   h3     = (u16*)  alloc((size_t)NN*HD*2);
  int*   cnt    = (int*)h3;
  int*   bsum   = (int*)((char*)h3 + (size_t)NRSEG*4);

  const int* src_in = eidx;        // edge_index[0]
  const int* dst_in = eidx + EE;   // edge_index[1]

  k_detect <<<1, 256, 0, stream>>>((const u32*)x, flag);
  hipMemsetAsync(cnt, 0, (size_t)NRSEG*4, stream);
  k_quant  <<<(NN*HD/4 + 255)/256, 256, 0, stream>>>(x, xq, flag);
  k_hist   <<<EE/256,    256, 0, stream>>>(dst_in, etype, cnt);
  k_scan1  <<<NRSEG/256, 256, 0, stream>>>(cnt, off, bsum);
  k_scan2  <<<1,        1024, 0, stream>>>(bsum, NRSEG/256);
  k_scan3  <<<NRSEG/256, 256, 0, stream>>>(cnt, off, bsum);
  k_scatter<<<EE/256,    256, 0, stream>>>(src_in, dst_in, etype, off, cnt, esrc);

  const int nblk = NN / TN;   // 3125, exact
  // layer 1: xq -> h1q (fp8)
  k_weights<<<1088, 256, 0, stream>>>(basesA[0], compA[0], rootA[0], WTf, flag);
  k_layer<<<nblk, 256, 0, stream>>>(xq,  WTf, biasA[0], off, esrc, (u16*)0, h1q, flag, 0, 1);
  // layer 2: h1q -> h2q (fp8)
  k_weights<<<1088, 256, 0, stream>>>(basesA[1], compA[1], rootA[1], WTf, flag);
  k_layer<<<nblk, 256, 0, stream>>>(h1q, WTf, biasA[1], off, esrc, (u16*)0, h2q, flag, 0, 1);
  // layer 3: h2q -> h3 (bf16, no relu)
  k_weights<<<1088, 256, 0, stream>>>(basesA[2], compA[2], rootA[2], WTf, flag);
  k_layer<<<nblk, 256, 0, stream>>>(h2q, WTf, biasA[2], off, esrc, h3, (u8*)0, flag, 1, 0);

  k_pool_head<<<NG, 1024, 0, stream>>>(h3, batch, rlab, rel_emb, lin_w, lin_b,
                                       d_out, flag);
}